// Round 1
// baseline (942.037 us; speedup 1.0000x reference)
//
#include <hip/hip_runtime.h>

#define N_NODES 100000
#define N_EDGES 1600000

// ---------------- kernels ----------------

__global__ void k_fill_one(int* __restrict__ deg, int n) {
    int i = blockIdx.x * blockDim.x + threadIdx.x;
    if (i < n) deg[i] = 1;  // self-loop
}

__global__ void k_deg(const int* __restrict__ dst, int* __restrict__ deg, int e) {
    int i = blockIdx.x * blockDim.x + threadIdx.x;
    if (i < e) atomicAdd(&deg[dst[i]], 1);
}

__global__ void k_dinv(float* __restrict__ dinv_io, int n) {
    int i = blockIdx.x * blockDim.x + threadIdx.x;
    if (i < n) {
        int d = ((const int*)dinv_io)[i];
        dinv_io[i] = rsqrtf((float)d);
    }
}

// G[node][c] = dinv[node] * sum_k X[node][k] * W[k][c],  c in [0,64)
template <int IC>
__global__ void k_gemm_scale(const float* __restrict__ X, const float* __restrict__ W,
                             const float* __restrict__ dinv, float* __restrict__ G, int n) {
    __shared__ float Ws[IC * 64];
    for (int i = threadIdx.x; i < IC * 64; i += blockDim.x) Ws[i] = W[i];
    __syncthreads();
    int idx = blockIdx.x * blockDim.x + threadIdx.x;
    int node = idx >> 6;
    int c = idx & 63;
    if (node >= n) return;
    const float* xr = X + (size_t)node * IC;
    float acc = 0.f;
#pragma unroll
    for (int k = 0; k < IC; ++k) acc += xr[k] * Ws[k * 64 + c];
    G[(size_t)node * 64 + c] = acc * dinv[node];
}

__global__ void k_copy4(const float4* __restrict__ src, float4* __restrict__ dst, int n4) {
    int i = blockIdx.x * blockDim.x + threadIdx.x;
    if (i < n4) dst[i] = src[i];
}

// one wave (64 lanes) per edge: lane c does acc[dst*64+c] += g[src*64+c]
__global__ void k_scatter(const int* __restrict__ src, const int* __restrict__ dst,
                          const float* __restrict__ G, float* __restrict__ acc, int e) {
    int idx = blockIdx.x * blockDim.x + threadIdx.x;
    int eid = idx >> 6;
    int c = idx & 63;
    if (eid >= e) return;
    int s = src[eid];
    int d = dst[eid];
    atomicAdd(&acc[(size_t)d * 64 + c], G[(size_t)s * 64 + c]);
}

__global__ void k_finish(const float* __restrict__ acc, const float* __restrict__ dinv,
                         const float* __restrict__ b, float* __restrict__ out, int n) {
    int idx = blockIdx.x * blockDim.x + threadIdx.x;
    if (idx >= n * 64) return;
    int node = idx >> 6;
    int c = idx & 63;
    float v = acc[idx] * dinv[node] + b[c];
    out[idx] = v > 0.f ? v : 0.f;
}

// ---------------- launch ----------------

extern "C" void kernel_launch(void* const* d_in, const int* in_sizes, int n_in,
                              void* d_out, int out_size, void* d_ws, size_t ws_size,
                              hipStream_t stream) {
    const float* x  = (const float*)d_in[0];
    const int* ei   = (const int*)d_in[1];   // [2, E] row-major, int32
    const float* W1 = (const float*)d_in[2];
    const float* b1 = (const float*)d_in[3];
    const float* W2 = (const float*)d_in[4];
    const float* b2 = (const float*)d_in[5];

    const int N = N_NODES;
    const int E = N_EDGES;
    const int* src = ei;       // edge_index[0]
    const int* dst = ei + E;   // edge_index[1]

    // workspace layout: [dinv: N floats][bufA: N*64 floats]
    char* ws = (char*)d_ws;
    float* dinv = (float*)ws;
    size_t dinv_bytes = ((size_t)N * 4 + 511) & ~511ull;
    float* bufA = (float*)(ws + dinv_bytes);       // 25.6 MB
    float* outF = (float*)d_out;                   // doubles as second buffer

    const int B = 256;
    const int NC = N * 64;  // 6.4M

    // degrees + dinv (shared by both layers)
    k_fill_one<<<(N + B - 1) / B, B, 0, stream>>>((int*)dinv, N);
    k_deg<<<(E + B - 1) / B, B, 0, stream>>>(dst, (int*)dinv, E);
    k_dinv<<<(N + B - 1) / B, B, 0, stream>>>(dinv, N);

    // ---- layer 1 ----
    // g1 = dinv * (x @ W1)   -> bufA
    k_gemm_scale<32><<<(NC + B - 1) / B, B, 0, stream>>>(x, W1, dinv, bufA, N);
    // acc1 = g1 (self loop)  -> d_out
    k_copy4<<<(NC / 4 + B - 1) / B, B, 0, stream>>>((const float4*)bufA, (float4*)outF, NC / 4);
    // acc1[dst] += g1[src]
    k_scatter<<<((size_t)E * 64 + B - 1) / B, B, 0, stream>>>(src, dst, bufA, outF, E);
    // h1 = relu(dinv*acc1 + b1) -> bufA (g1 dead now)
    k_finish<<<(NC + B - 1) / B, B, 0, stream>>>(outF, dinv, b1, bufA, N);

    // ---- layer 2 ----
    // g2 = dinv * (h1 @ W2)  -> d_out (acc1 dead)
    k_gemm_scale<64><<<(NC + B - 1) / B, B, 0, stream>>>(bufA, W2, dinv, outF, N);
    // acc2 = g2              -> bufA (h1 dead)
    k_copy4<<<(NC / 4 + B - 1) / B, B, 0, stream>>>((const float4*)outF, (float4*)bufA, NC / 4);
    // acc2[dst] += g2[src]
    k_scatter<<<((size_t)E * 64 + B - 1) / B, B, 0, stream>>>(src, dst, outF, bufA, E);
    // out = relu(dinv*acc2 + b2) -> d_out (g2 dead)
    k_finish<<<(NC + B - 1) / B, B, 0, stream>>>(bufA, dinv, b2, outF, N);
}

// Round 2
// 528.239 us; speedup vs baseline: 1.7834x; 1.7834x over previous
//
#include <hip/hip_runtime.h>

#define N_NODES 100000
#define N_EDGES 1600000

// ---------------- CSR build ----------------

__global__ void k_zero(int* __restrict__ p, int n) {
    int i = blockIdx.x * blockDim.x + threadIdx.x;
    if (i < n) p[i] = 0;
}

__global__ void k_deg(const int* __restrict__ dst, int* __restrict__ degI, int e) {
    int i = blockIdx.x * blockDim.x + threadIdx.x;
    if (i < e) atomicAdd(&degI[dst[i]], 1);
}

__global__ void k_dinv(const int* __restrict__ degI, float* __restrict__ dinv, int n) {
    int i = blockIdx.x * blockDim.x + threadIdx.x;
    if (i < n) dinv[i] = rsqrtf((float)(1 + degI[i]));  // +1 = self-loop
}

// single-block exclusive scan of degI -> rowptr (and cursor copy), 1024 thr, 4 elem/thr
__global__ void k_scan(const int* __restrict__ degI, int* __restrict__ rowptr,
                       int* __restrict__ cursor, int n, int total) {
    __shared__ int wsum[16];
    __shared__ int carry_s;
    if (threadIdx.x == 0) carry_s = 0;
    __syncthreads();
    const int lane = threadIdx.x & 63;
    const int wid = threadIdx.x >> 6;
    for (int base = 0; base < n; base += 4096) {
        int i0 = base + threadIdx.x * 4;
        int v[4];
#pragma unroll
        for (int k = 0; k < 4; ++k) {
            int i = i0 + k;
            v[k] = (i < n) ? degI[i] : 0;
        }
        int tsum = v[0] + v[1] + v[2] + v[3];
        // inclusive wave scan of per-thread sums
        int sc = tsum;
#pragma unroll
        for (int off = 1; off < 64; off <<= 1) {
            int t = __shfl_up(sc, off, 64);
            if (lane >= off) sc += t;
        }
        if (lane == 63) wsum[wid] = sc;
        __syncthreads();
        if (threadIdx.x == 0) {
            int run = carry_s;
#pragma unroll
            for (int w = 0; w < 16; ++w) { int t = wsum[w]; wsum[w] = run; run += t; }
            carry_s = run;
        }
        __syncthreads();
        int e0 = wsum[wid] + (sc - tsum);  // exclusive prefix for this thread
#pragma unroll
        for (int k = 0; k < 4; ++k) {
            int i = i0 + k;
            if (i < n) { rowptr[i] = e0; cursor[i] = e0; }
            e0 += v[k];
        }
        __syncthreads();  // wsum reused next chunk
    }
    if (threadIdx.x == 0) rowptr[n] = total;
}

__global__ void k_fill(const int* __restrict__ src, const int* __restrict__ dst,
                       int* __restrict__ cursor, int* __restrict__ col, int e) {
    int i = blockIdx.x * blockDim.x + threadIdx.x;
    if (i < e) {
        int p = atomicAdd(&cursor[dst[i]], 1);
        col[p] = src[i];
    }
}

// ---------------- per-layer kernels ----------------

// G[node][c] = dinv[node] * sum_k X[node][k] * W[k][c],  c in [0,64)
template <int IC>
__global__ void k_gemm_scale(const float* __restrict__ X, const float* __restrict__ W,
                             const float* __restrict__ dinv, float* __restrict__ G, int n) {
    __shared__ float Ws[IC * 64];
    for (int i = threadIdx.x; i < IC * 64; i += blockDim.x) Ws[i] = W[i];
    __syncthreads();
    int idx = blockIdx.x * blockDim.x + threadIdx.x;
    int node = idx >> 6;
    int c = idx & 63;
    if (node >= n) return;
    const float* xr = X + (size_t)node * IC;
    float acc = 0.f;
#pragma unroll
    for (int k = 0; k < IC; ++k) acc += xr[k] * Ws[k * 64 + c];
    G[(size_t)node * 64 + c] = acc * dinv[node];
}

// out[node] = relu(dinv[node] * (g[node] + sum_{in-edges} g[src]) + b)
// 16 lanes per node, float4 per lane (64 channels)
__global__ void k_gather(const float4* __restrict__ G4, const int* __restrict__ rowptr,
                         const int* __restrict__ col, const float* __restrict__ dinv,
                         const float* __restrict__ b, float4* __restrict__ out4, int n) {
    int idx = blockIdx.x * blockDim.x + threadIdx.x;
    int node = idx >> 4;
    int l = idx & 15;
    if (node >= n) return;
    float4 acc = G4[(size_t)node * 16 + l];  // self-loop term (pre-scaled by dinv[node])
    int jb = rowptr[node], je = rowptr[node + 1];
    int j = jb;
    for (; j + 1 < je; j += 2) {
        int s0 = col[j], s1 = col[j + 1];
        float4 v0 = G4[(size_t)s0 * 16 + l];
        float4 v1 = G4[(size_t)s1 * 16 + l];
        acc.x += v0.x + v1.x;
        acc.y += v0.y + v1.y;
        acc.z += v0.z + v1.z;
        acc.w += v0.w + v1.w;
    }
    if (j < je) {
        int s0 = col[j];
        float4 v0 = G4[(size_t)s0 * 16 + l];
        acc.x += v0.x; acc.y += v0.y; acc.z += v0.z; acc.w += v0.w;
    }
    float di = dinv[node];
    float4 bb = ((const float4*)b)[l];
    float4 r;
    r.x = fmaxf(acc.x * di + bb.x, 0.f);
    r.y = fmaxf(acc.y * di + bb.y, 0.f);
    r.z = fmaxf(acc.z * di + bb.z, 0.f);
    r.w = fmaxf(acc.w * di + bb.w, 0.f);
    out4[(size_t)node * 16 + l] = r;
}

// ---------------- launch ----------------

extern "C" void kernel_launch(void* const* d_in, const int* in_sizes, int n_in,
                              void* d_out, int out_size, void* d_ws, size_t ws_size,
                              hipStream_t stream) {
    const float* x  = (const float*)d_in[0];
    const int* ei   = (const int*)d_in[1];   // [2, E] row-major, int32
    const float* W1 = (const float*)d_in[2];
    const float* b1 = (const float*)d_in[3];
    const float* W2 = (const float*)d_in[4];
    const float* b2 = (const float*)d_in[5];

    const int N = N_NODES;
    const int E = N_EDGES;
    const int* src = ei;       // edge_index[0]
    const int* dst = ei + E;   // edge_index[1]

    // workspace layout (all 512B aligned):
    char* ws = (char*)d_ws;
    size_t off = 0;
    auto alloc = [&](size_t bytes) { void* p = ws + off; off = (off + bytes + 511) & ~511ull; return p; };
    int*   degI   = (int*)  alloc((size_t)N * 4);
    float* dinv   = (float*)alloc((size_t)N * 4);
    int*   rowptr = (int*)  alloc((size_t)(N + 1) * 4);
    int*   cursor = (int*)  alloc((size_t)N * 4);
    int*   col    = (int*)  alloc((size_t)E * 4);
    float* bufA   = (float*)alloc((size_t)N * 64 * 4);  // 25.6 MB
    float* outF   = (float*)d_out;

    const int B = 256;
    const int NC = N * 64;

    // ---- CSR build (shared by both layers) ----
    k_zero<<<(N + B - 1) / B, B, 0, stream>>>(degI, N);
    k_deg<<<(E + B - 1) / B, B, 0, stream>>>(dst, degI, E);
    k_dinv<<<(N + B - 1) / B, B, 0, stream>>>(degI, dinv, N);
    k_scan<<<1, 1024, 0, stream>>>(degI, rowptr, cursor, N, E);
    k_fill<<<(E + B - 1) / B, B, 0, stream>>>(src, dst, cursor, col, E);

    // ---- layer 1 ----
    k_gemm_scale<32><<<(NC + B - 1) / B, B, 0, stream>>>(x, W1, dinv, bufA, N);
    k_gather<<<((size_t)N * 16 + B - 1) / B, B, 0, stream>>>(
        (const float4*)bufA, rowptr, col, dinv, b1, (float4*)outF, N);

    // ---- layer 2 ----
    k_gemm_scale<64><<<(NC + B - 1) / B, B, 0, stream>>>(outF, W2, dinv, bufA, N);
    k_gather<<<((size_t)N * 16 + B - 1) / B, B, 0, stream>>>(
        (const float4*)bufA, rowptr, col, dinv, b2, (float4*)outF, N);
}

// Round 3
// 308.554 us; speedup vs baseline: 3.0531x; 1.7120x over previous
//
#include <hip/hip_runtime.h>

#define N_NODES 100000
#define N_EDGES 1600000
#define BSHIFT 9
#define BNODES 512                                  // nodes per bucket (2^BSHIFT)
#define NB ((N_NODES + BNODES - 1) / BNODES)        // 196 buckets
#define NBP 256                                     // padded for scans
#define TILE 4096
#define EPT 16                                      // edges/thread in redistribute (256 thr)

// ---------------- CSR build (bucketed counting sort) ----------------

__global__ void k_hist(const int* __restrict__ dst, int* __restrict__ bucketCnt, int e) {
    __shared__ int h[NBP];
    for (int i = threadIdx.x; i < NBP; i += blockDim.x) h[i] = 0;
    __syncthreads();
    int stride = gridDim.x * blockDim.x;
    for (int i = blockIdx.x * blockDim.x + threadIdx.x; i < e; i += stride)
        atomicAdd(&h[dst[i] >> BSHIFT], 1);
    __syncthreads();
    for (int i = threadIdx.x; i < NB; i += blockDim.x)
        if (h[i]) atomicAdd(&bucketCnt[i], h[i]);
}

__global__ void k_bscan(const int* __restrict__ bucketCnt, int* __restrict__ bucketBase,
                        int* __restrict__ bucketCur) {
    __shared__ int a[NBP];
    int t = threadIdx.x;  // 256 threads
    a[t] = (t < NB) ? bucketCnt[t] : 0;
    __syncthreads();
    for (int off = 1; off < NBP; off <<= 1) {
        int v = (t >= off) ? a[t - off] : 0;
        __syncthreads();
        a[t] += v;
        __syncthreads();
    }
    if (t < NB) {
        int incl = a[t];
        int excl = incl - bucketCnt[t];
        bucketBase[t] = excl;
        bucketCur[t] = excl;
        if (t == NB - 1) bucketBase[NB] = incl;
    }
}

// tile-local counting sort by bucket, then coalesced append into global packed[]
__global__ __launch_bounds__(256) void k_redistribute(
        const int* __restrict__ src, const int* __restrict__ dst,
        int* __restrict__ bucketCur, int* __restrict__ packed, int e) {
    __shared__ int cnt[NBP], base[NBP], gdelta[NBP], lcur[NBP], a[NBP];
    __shared__ int sorted[TILE];
    __shared__ int sdelta[TILE];
    int tileBase = blockIdx.x * TILE;
    int tileCnt = min(TILE, e - tileBase);
    int t = threadIdx.x;
    for (int i = t; i < NBP; i += 256) cnt[i] = 0;
    __syncthreads();
    int pk[EPT], bk[EPT];
#pragma unroll
    for (int k = 0; k < EPT; ++k) {
        int i = k * 256 + t;
        if (i < tileCnt) {
            int d = dst[tileBase + i];
            int s = src[tileBase + i];
            bk[k] = d >> BSHIFT;
            pk[k] = (s << BSHIFT) | (d & (BNODES - 1));
            atomicAdd(&cnt[bk[k]], 1);
        } else bk[k] = -1;
    }
    __syncthreads();
    a[t] = cnt[t];
    __syncthreads();
    for (int off = 1; off < NBP; off <<= 1) {
        int v = (t >= off) ? a[t - off] : 0;
        __syncthreads();
        a[t] += v;
        __syncthreads();
    }
    base[t] = a[t] - cnt[t];
    lcur[t] = base[t];
    if (t < NB && cnt[t] > 0)
        gdelta[t] = atomicAdd(&bucketCur[t], cnt[t]) - base[t];
    __syncthreads();
#pragma unroll
    for (int k = 0; k < EPT; ++k) {
        if (bk[k] >= 0) {
            int l = atomicAdd(&lcur[bk[k]], 1);
            sorted[l] = pk[k];
            sdelta[l] = gdelta[bk[k]];
        }
    }
    __syncthreads();
    for (int i = t; i < tileCnt; i += 256)
        packed[i + sdelta[i]] = sorted[i];
}

// one WG per bucket: per-node histogram -> rowptr + dinv, then local col scatter
__global__ __launch_bounds__(512) void k_bucket_csr(
        const int* __restrict__ packed, const int* __restrict__ bucketBase,
        int* __restrict__ rowptr, int* __restrict__ col, float* __restrict__ dinv,
        int n, int e) {
    __shared__ int hist[BNODES], a[BNODES], cur[BNODES];
    int b = blockIdx.x;
    int node0 = b * BNODES;
    int nn = min(BNODES, n - node0);
    int eb = bucketBase[b], ee = bucketBase[b + 1];
    int t = threadIdx.x;  // 512 threads
    hist[t] = 0;
    __syncthreads();
    for (int i = eb + t; i < ee; i += 512)
        atomicAdd(&hist[packed[i] & (BNODES - 1)], 1);
    __syncthreads();
    a[t] = hist[t];
    __syncthreads();
    for (int off = 1; off < BNODES; off <<= 1) {
        int v = (t >= off) ? a[t - off] : 0;
        __syncthreads();
        a[t] += v;
        __syncthreads();
    }
    int excl = a[t] - hist[t];
    cur[t] = excl;
    if (t < nn) {
        rowptr[node0 + t] = eb + excl;
        dinv[node0 + t] = rsqrtf((float)(1 + hist[t]));
    }
    if (b == gridDim.x - 1 && t == 0) rowptr[n] = e;
    __syncthreads();
    for (int i = eb + t; i < ee; i += 512) {
        int p = packed[i];
        int dl = p & (BNODES - 1);
        int l = atomicAdd(&cur[dl], 1);
        col[eb + l] = p >> BSHIFT;
    }
}

// ---------------- per-layer kernels ----------------

// G[node][c] = dinv[node] * sum_k X[node][k] * W[k][c],  c in [0,64)
template <int IC>
__global__ void k_gemm_scale(const float* __restrict__ X, const float* __restrict__ W,
                             const float* __restrict__ dinv, float* __restrict__ G, int n) {
    __shared__ float Ws[IC * 64];
    for (int i = threadIdx.x; i < IC * 64; i += blockDim.x) Ws[i] = W[i];
    __syncthreads();
    int idx = blockIdx.x * blockDim.x + threadIdx.x;
    int node = idx >> 6;
    int c = idx & 63;
    if (node >= n) return;
    const float* xr = X + (size_t)node * IC;
    float acc = 0.f;
#pragma unroll
    for (int k = 0; k < IC; ++k) acc += xr[k] * Ws[k * 64 + c];
    G[(size_t)node * 64 + c] = acc * dinv[node];
}

// out[node] = relu(dinv[node] * (g[node] + sum_{in-edges} g[src]) + b)
// 16 lanes per node, float4 per lane (64 channels)
__global__ void k_gather(const float4* __restrict__ G4, const int* __restrict__ rowptr,
                         const int* __restrict__ col, const float* __restrict__ dinv,
                         const float* __restrict__ b, float4* __restrict__ out4, int n) {
    int idx = blockIdx.x * blockDim.x + threadIdx.x;
    int node = idx >> 4;
    int l = idx & 15;
    if (node >= n) return;
    float4 acc = G4[(size_t)node * 16 + l];  // self-loop term (pre-scaled by dinv[node])
    int jb = rowptr[node], je = rowptr[node + 1];
    int j = jb;
    for (; j + 1 < je; j += 2) {
        int s0 = col[j], s1 = col[j + 1];
        float4 v0 = G4[(size_t)s0 * 16 + l];
        float4 v1 = G4[(size_t)s1 * 16 + l];
        acc.x += v0.x + v1.x;
        acc.y += v0.y + v1.y;
        acc.z += v0.z + v1.z;
        acc.w += v0.w + v1.w;
    }
    if (j < je) {
        int s0 = col[j];
        float4 v0 = G4[(size_t)s0 * 16 + l];
        acc.x += v0.x; acc.y += v0.y; acc.z += v0.z; acc.w += v0.w;
    }
    float di = dinv[node];
    float4 bb = ((const float4*)b)[l];
    float4 r;
    r.x = fmaxf(acc.x * di + bb.x, 0.f);
    r.y = fmaxf(acc.y * di + bb.y, 0.f);
    r.z = fmaxf(acc.z * di + bb.z, 0.f);
    r.w = fmaxf(acc.w * di + bb.w, 0.f);
    out4[(size_t)node * 16 + l] = r;
}

// ---------------- launch ----------------

extern "C" void kernel_launch(void* const* d_in, const int* in_sizes, int n_in,
                              void* d_out, int out_size, void* d_ws, size_t ws_size,
                              hipStream_t stream) {
    const float* x  = (const float*)d_in[0];
    const int* ei   = (const int*)d_in[1];   // [2, E] row-major, int32
    const float* W1 = (const float*)d_in[2];
    const float* b1 = (const float*)d_in[3];
    const float* W2 = (const float*)d_in[4];
    const float* b2 = (const float*)d_in[5];

    const int N = N_NODES;
    const int E = N_EDGES;
    const int* src = ei;       // edge_index[0]
    const int* dst = ei + E;   // edge_index[1]

    // workspace layout (512B aligned blocks)
    char* ws = (char*)d_ws;
    size_t off = 0;
    auto alloc = [&](size_t bytes) { void* p = ws + off; off = (off + bytes + 511) & ~511ull; return p; };
    int*   bucketCnt  = (int*)  alloc((size_t)NB * 4);
    int*   bucketBase = (int*)  alloc((size_t)(NB + 1) * 4);
    int*   bucketCur  = (int*)  alloc((size_t)NB * 4);
    int*   packed     = (int*)  alloc((size_t)E * 4);
    int*   rowptr     = (int*)  alloc((size_t)(N + 1) * 4);
    int*   col        = (int*)  alloc((size_t)E * 4);
    float* dinv       = (float*)alloc((size_t)N * 4);
    float* bufA       = (float*)alloc((size_t)N * 64 * 4);  // 25.6 MB
    float* outF       = (float*)d_out;

    const int B = 256;
    const int NC = N * 64;
    const int nTiles = (E + TILE - 1) / TILE;  // 391

    // ---- CSR build ----
    hipMemsetAsync(bucketCnt, 0, (size_t)NB * 4, stream);
    k_hist<<<256, B, 0, stream>>>(dst, bucketCnt, E);
    k_bscan<<<1, NBP, 0, stream>>>(bucketCnt, bucketBase, bucketCur);
    k_redistribute<<<nTiles, B, 0, stream>>>(src, dst, bucketCur, packed, E);
    k_bucket_csr<<<NB, BNODES, 0, stream>>>(packed, bucketBase, rowptr, col, dinv, N, E);

    // ---- layer 1 ----
    k_gemm_scale<32><<<(NC + B - 1) / B, B, 0, stream>>>(x, W1, dinv, bufA, N);
    k_gather<<<((size_t)N * 16 + B - 1) / B, B, 0, stream>>>(
        (const float4*)bufA, rowptr, col, dinv, b1, (float4*)outF, N);

    // ---- layer 2 ----
    k_gemm_scale<64><<<(NC + B - 1) / B, B, 0, stream>>>(outF, W2, dinv, bufA, N);
    k_gather<<<((size_t)N * 16 + B - 1) / B, B, 0, stream>>>(
        (const float4*)bufA, rowptr, col, dinv, b2, (float4*)outF, N);
}

// Round 4
// 244.211 us; speedup vs baseline: 3.8575x; 1.2635x over previous
//
#include <hip/hip_runtime.h>

#define N_NODES 100000
#define N_EDGES 1600000
#define BSHIFT 9
#define BNODES 512                                  // nodes per bucket (2^BSHIFT)
#define NB ((N_NODES + BNODES - 1) / BNODES)        // 196 buckets
#define NBP 256                                     // padded for scans
#define TILE 4096
#define EPT 16                                      // edges/thread in redistribute (256 thr)

// ---------------- CSR build (bucketed counting sort) ----------------

__global__ void k_hist(const int* __restrict__ dst, int* __restrict__ bucketCnt, int e) {
    __shared__ int h[NBP];
    for (int i = threadIdx.x; i < NBP; i += blockDim.x) h[i] = 0;
    __syncthreads();
    int stride = gridDim.x * blockDim.x;
    for (int i = blockIdx.x * blockDim.x + threadIdx.x; i < e; i += stride)
        atomicAdd(&h[dst[i] >> BSHIFT], 1);
    __syncthreads();
    for (int i = threadIdx.x; i < NB; i += blockDim.x)
        if (h[i]) atomicAdd(&bucketCnt[i], h[i]);
}

__global__ void k_bscan(const int* __restrict__ bucketCnt, int* __restrict__ bucketBase,
                        int* __restrict__ bucketCur) {
    __shared__ int a[NBP];
    int t = threadIdx.x;  // 256 threads
    a[t] = (t < NB) ? bucketCnt[t] : 0;
    __syncthreads();
    for (int off = 1; off < NBP; off <<= 1) {
        int v = (t >= off) ? a[t - off] : 0;
        __syncthreads();
        a[t] += v;
        __syncthreads();
    }
    if (t < NB) {
        int incl = a[t];
        int excl = incl - bucketCnt[t];
        bucketBase[t] = excl;
        bucketCur[t] = excl;
        if (t == NB - 1) bucketBase[NB] = incl;
    }
}

// tile-local counting sort by bucket, then coalesced append into global packed[]
__global__ __launch_bounds__(256) void k_redistribute(
        const int* __restrict__ src, const int* __restrict__ dst,
        int* __restrict__ bucketCur, int* __restrict__ packed, int e) {
    __shared__ int cnt[NBP], base[NBP], gdelta[NBP], lcur[NBP], a[NBP];
    __shared__ int sorted[TILE];
    __shared__ int sdelta[TILE];
    int tileBase = blockIdx.x * TILE;
    int tileCnt = min(TILE, e - tileBase);
    int t = threadIdx.x;
    for (int i = t; i < NBP; i += 256) cnt[i] = 0;
    __syncthreads();
    int pk[EPT], bk[EPT];
#pragma unroll
    for (int k = 0; k < EPT; ++k) {
        int i = k * 256 + t;
        if (i < tileCnt) {
            int d = dst[tileBase + i];
            int s = src[tileBase + i];
            bk[k] = d >> BSHIFT;
            pk[k] = (s << BSHIFT) | (d & (BNODES - 1));
            atomicAdd(&cnt[bk[k]], 1);
        } else bk[k] = -1;
    }
    __syncthreads();
    a[t] = cnt[t];
    __syncthreads();
    for (int off = 1; off < NBP; off <<= 1) {
        int v = (t >= off) ? a[t - off] : 0;
        __syncthreads();
        a[t] += v;
        __syncthreads();
    }
    base[t] = a[t] - cnt[t];
    lcur[t] = base[t];
    if (t < NB && cnt[t] > 0)
        gdelta[t] = atomicAdd(&bucketCur[t], cnt[t]) - base[t];
    __syncthreads();
#pragma unroll
    for (int k = 0; k < EPT; ++k) {
        if (bk[k] >= 0) {
            int l = atomicAdd(&lcur[bk[k]], 1);
            sorted[l] = pk[k];
            sdelta[l] = gdelta[bk[k]];
        }
    }
    __syncthreads();
    for (int i = t; i < tileCnt; i += 256)
        packed[i + sdelta[i]] = sorted[i];
}

// one WG per bucket: per-node histogram -> rowptr + dinv, then local col scatter
__global__ __launch_bounds__(512) void k_bucket_csr(
        const int* __restrict__ packed, const int* __restrict__ bucketBase,
        int* __restrict__ rowptr, int* __restrict__ col, float* __restrict__ dinv,
        int n, int e) {
    __shared__ int hist[BNODES], a[BNODES], cur[BNODES];
    int b = blockIdx.x;
    int node0 = b * BNODES;
    int nn = min(BNODES, n - node0);
    int eb = bucketBase[b], ee = bucketBase[b + 1];
    int t = threadIdx.x;  // 512 threads
    hist[t] = 0;
    __syncthreads();
    for (int i = eb + t; i < ee; i += 512)
        atomicAdd(&hist[packed[i] & (BNODES - 1)], 1);
    __syncthreads();
    a[t] = hist[t];
    __syncthreads();
    for (int off = 1; off < BNODES; off <<= 1) {
        int v = (t >= off) ? a[t - off] : 0;
        __syncthreads();
        a[t] += v;
        __syncthreads();
    }
    int excl = a[t] - hist[t];
    cur[t] = excl;
    if (t < nn) {
        rowptr[node0 + t] = eb + excl;
        dinv[node0 + t] = rsqrtf((float)(1 + hist[t]));
    }
    if (b == gridDim.x - 1 && t == 0) rowptr[n] = e;
    __syncthreads();
    for (int i = eb + t; i < ee; i += 512) {
        int p = packed[i];
        int dl = p & (BNODES - 1);
        int l = atomicAdd(&cur[dl], 1);
        col[eb + l] = p >> BSHIFT;
    }
}

// ---------------- per-layer kernels ----------------

// Register-blocked tiled GEMM: G[node][c] = dinv[node] * sum_k X[node][k] * W[k][c]
// 64 nodes x 64 channels per 256-thread block; each thread: 4 nodes x 4 channels.
template <int IC>
__global__ __launch_bounds__(256) void k_gemm_tiled(
        const float* __restrict__ X, const float* __restrict__ W,
        const float* __restrict__ dinv, float* __restrict__ G, int n) {
    constexpr int STR = IC + 4;           // pad -> 2-way banks on x reads (free)
    __shared__ float Xs[64 * STR];
    __shared__ float Ws[IC * 64];
    const int t = threadIdx.x;
    const int node0 = blockIdx.x * 64;

    // stage W (float4 coalesced)
#pragma unroll 2
    for (int i = t; i < IC * 16; i += 256)
        ((float4*)Ws)[i] = ((const float4*)W)[i];

    // stage X tile (float4 coalesced, guarded)
    constexpr int NF4 = 64 * IC / 4;      // 1024 (IC=64) or 512 (IC=32)
    const float4* X4 = (const float4*)(X + (size_t)node0 * IC);
#pragma unroll 2
    for (int i = t; i < NF4; i += 256) {
        int node = i / (IC / 4);
        int k0 = (i % (IC / 4)) * 4;
        float4 v = make_float4(0.f, 0.f, 0.f, 0.f);
        if (node0 + node < n) v = X4[i];
        *(float4*)&Xs[node * STR + k0] = v;
    }
    __syncthreads();

    const int ng = t >> 4;   // 0..15 -> nodes ng*4..ng*4+3
    const int cg = t & 15;   // 0..15 -> channels cg*4..cg*4+3
    const float* xr0 = &Xs[(ng * 4 + 0) * STR];
    const float* xr1 = &Xs[(ng * 4 + 1) * STR];
    const float* xr2 = &Xs[(ng * 4 + 2) * STR];
    const float* xr3 = &Xs[(ng * 4 + 3) * STR];
    const float4* Ws4 = (const float4*)Ws;

    float4 acc0 = {0, 0, 0, 0}, acc1 = {0, 0, 0, 0}, acc2 = {0, 0, 0, 0}, acc3 = {0, 0, 0, 0};

#pragma unroll
    for (int k = 0; k < IC; k += 4) {
        float xa[4], xb[4], xc[4], xd[4];
        *(float4*)xa = *(const float4*)&xr0[k];
        *(float4*)xb = *(const float4*)&xr1[k];
        *(float4*)xc = *(const float4*)&xr2[k];
        *(float4*)xd = *(const float4*)&xr3[k];
#pragma unroll
        for (int j = 0; j < 4; ++j) {
            float4 w4 = Ws4[(k + j) * 16 + cg];
            acc0.x += xa[j] * w4.x; acc0.y += xa[j] * w4.y; acc0.z += xa[j] * w4.z; acc0.w += xa[j] * w4.w;
            acc1.x += xb[j] * w4.x; acc1.y += xb[j] * w4.y; acc1.z += xb[j] * w4.z; acc1.w += xb[j] * w4.w;
            acc2.x += xc[j] * w4.x; acc2.y += xc[j] * w4.y; acc2.z += xc[j] * w4.z; acc2.w += xc[j] * w4.w;
            acc3.x += xd[j] * w4.x; acc3.y += xd[j] * w4.y; acc3.z += xd[j] * w4.z; acc3.w += xd[j] * w4.w;
        }
    }

    // epilogue: scale by dinv[node], store float4
    float4* G4 = (float4*)G;
    int nb = ng * 4;
    float4 accs[4] = {acc0, acc1, acc2, acc3};
#pragma unroll
    for (int i = 0; i < 4; ++i) {
        int node = node0 + nb + i;
        if (node < n) {
            float di = dinv[node];
            float4 r;
            r.x = accs[i].x * di; r.y = accs[i].y * di;
            r.z = accs[i].z * di; r.w = accs[i].w * di;
            G4[(size_t)node * 16 + cg] = r;
        }
    }
}

// out[node] = relu(dinv[node] * (g[node] + sum_{in-edges} g[src]) + b)
// 16 lanes per node, float4 per lane (64 channels)
__global__ void k_gather(const float4* __restrict__ G4, const int* __restrict__ rowptr,
                         const int* __restrict__ col, const float* __restrict__ dinv,
                         const float* __restrict__ b, float4* __restrict__ out4, int n) {
    int idx = blockIdx.x * blockDim.x + threadIdx.x;
    int node = idx >> 4;
    int l = idx & 15;
    if (node >= n) return;
    float4 acc = G4[(size_t)node * 16 + l];  // self-loop term (pre-scaled by dinv[node])
    int jb = rowptr[node], je = rowptr[node + 1];
    int j = jb;
    for (; j + 1 < je; j += 2) {
        int s0 = col[j], s1 = col[j + 1];
        float4 v0 = G4[(size_t)s0 * 16 + l];
        float4 v1 = G4[(size_t)s1 * 16 + l];
        acc.x += v0.x + v1.x;
        acc.y += v0.y + v1.y;
        acc.z += v0.z + v1.z;
        acc.w += v0.w + v1.w;
    }
    if (j < je) {
        int s0 = col[j];
        float4 v0 = G4[(size_t)s0 * 16 + l];
        acc.x += v0.x; acc.y += v0.y; acc.z += v0.z; acc.w += v0.w;
    }
    float di = dinv[node];
    float4 bb = ((const float4*)b)[l];
    float4 r;
    r.x = fmaxf(acc.x * di + bb.x, 0.f);
    r.y = fmaxf(acc.y * di + bb.y, 0.f);
    r.z = fmaxf(acc.z * di + bb.z, 0.f);
    r.w = fmaxf(acc.w * di + bb.w, 0.f);
    out4[(size_t)node * 16 + l] = r;
}

// ---------------- launch ----------------

extern "C" void kernel_launch(void* const* d_in, const int* in_sizes, int n_in,
                              void* d_out, int out_size, void* d_ws, size_t ws_size,
                              hipStream_t stream) {
    const float* x  = (const float*)d_in[0];
    const int* ei   = (const int*)d_in[1];   // [2, E] row-major, int32
    const float* W1 = (const float*)d_in[2];
    const float* b1 = (const float*)d_in[3];
    const float* W2 = (const float*)d_in[4];
    const float* b2 = (const float*)d_in[5];

    const int N = N_NODES;
    const int E = N_EDGES;
    const int* src = ei;       // edge_index[0]
    const int* dst = ei + E;   // edge_index[1]

    // workspace layout (512B aligned blocks)
    char* ws = (char*)d_ws;
    size_t off = 0;
    auto alloc = [&](size_t bytes) { void* p = ws + off; off = (off + bytes + 511) & ~511ull; return p; };
    int*   bucketCnt  = (int*)  alloc((size_t)NB * 4);
    int*   bucketBase = (int*)  alloc((size_t)(NB + 1) * 4);
    int*   bucketCur  = (int*)  alloc((size_t)NB * 4);
    int*   packed     = (int*)  alloc((size_t)E * 4);
    int*   rowptr     = (int*)  alloc((size_t)(N + 1) * 4);
    int*   col        = (int*)  alloc((size_t)E * 4);
    float* dinv       = (float*)alloc((size_t)N * 4);
    float* bufA       = (float*)alloc((size_t)N * 64 * 4);  // 25.6 MB
    float* outF       = (float*)d_out;

    const int B = 256;
    const int nTiles = (E + TILE - 1) / TILE;  // 391
    const int nGBlocks = (N + 63) / 64;        // 1563

    // ---- CSR build ----
    hipMemsetAsync(bucketCnt, 0, (size_t)NB * 4, stream);
    k_hist<<<256, B, 0, stream>>>(dst, bucketCnt, E);
    k_bscan<<<1, NBP, 0, stream>>>(bucketCnt, bucketBase, bucketCur);
    k_redistribute<<<nTiles, B, 0, stream>>>(src, dst, bucketCur, packed, E);
    k_bucket_csr<<<NB, BNODES, 0, stream>>>(packed, bucketBase, rowptr, col, dinv, N, E);

    // ---- layer 1 ----
    k_gemm_tiled<32><<<nGBlocks, B, 0, stream>>>(x, W1, dinv, bufA, N);
    k_gather<<<((size_t)N * 16 + B - 1) / B, B, 0, stream>>>(
        (const float4*)bufA, rowptr, col, dinv, b1, (float4*)outF, N);

    // ---- layer 2 ----
    k_gemm_tiled<64><<<nGBlocks, B, 0, stream>>>(outF, W2, dinv, bufA, N);
    k_gather<<<((size_t)N * 16 + B - 1) / B, B, 0, stream>>>(
        (const float4*)bufA, rowptr, col, dinv, b2, (float4*)outF, N);
}

// Round 5
// 137.097 us; speedup vs baseline: 6.8713x; 1.7813x over previous
//
#include <hip/hip_runtime.h>

#define N_NODES 100000
#define N_EDGES 1600000
#define BSHIFT 9
#define BNODES 512                                  // nodes per bucket (2^BSHIFT)
#define NB ((N_NODES + BNODES - 1) / BNODES)        // 196 buckets
#define NBP 256                                     // padded for scans
#define TILE 4096
#define EPT 16                                      // edges/thread in redistribute (256 thr)

typedef _Float16 half8 __attribute__((ext_vector_type(8)));
typedef _Float16 half4 __attribute__((ext_vector_type(4)));
typedef float floatx4 __attribute__((ext_vector_type(4)));

// ---------------- CSR build (bucketed counting sort) ----------------

__global__ void k_hist(const int* __restrict__ dst, int* __restrict__ bucketCnt, int e) {
    __shared__ int h[NBP];
    for (int i = threadIdx.x; i < NBP; i += blockDim.x) h[i] = 0;
    __syncthreads();
    int stride = gridDim.x * blockDim.x;
    for (int i = blockIdx.x * blockDim.x + threadIdx.x; i < e; i += stride)
        atomicAdd(&h[dst[i] >> BSHIFT], 1);
    __syncthreads();
    for (int i = threadIdx.x; i < NB; i += blockDim.x)
        if (h[i]) atomicAdd(&bucketCnt[i], h[i]);
}

__global__ void k_bscan(const int* __restrict__ bucketCnt, int* __restrict__ bucketBase,
                        int* __restrict__ bucketCur) {
    __shared__ int a[NBP];
    int t = threadIdx.x;  // 256 threads
    a[t] = (t < NB) ? bucketCnt[t] : 0;
    __syncthreads();
    for (int off = 1; off < NBP; off <<= 1) {
        int v = (t >= off) ? a[t - off] : 0;
        __syncthreads();
        a[t] += v;
        __syncthreads();
    }
    if (t < NB) {
        int incl = a[t];
        int excl = incl - bucketCnt[t];
        bucketBase[t] = excl;
        bucketCur[t] = excl;
        if (t == NB - 1) bucketBase[NB] = incl;
    }
}

// tile-local counting sort by bucket, then coalesced append into global packed[]
__global__ __launch_bounds__(256) void k_redistribute(
        const int* __restrict__ src, const int* __restrict__ dst,
        int* __restrict__ bucketCur, int* __restrict__ packed, int e) {
    __shared__ int cnt[NBP], base[NBP], gdelta[NBP], lcur[NBP], a[NBP];
    __shared__ int sorted[TILE];
    __shared__ int sdelta[TILE];
    int tileBase = blockIdx.x * TILE;
    int tileCnt = min(TILE, e - tileBase);
    int t = threadIdx.x;
    for (int i = t; i < NBP; i += 256) cnt[i] = 0;
    __syncthreads();
    int pk[EPT], bk[EPT];
#pragma unroll
    for (int k = 0; k < EPT; ++k) {
        int i = k * 256 + t;
        if (i < tileCnt) {
            int d = dst[tileBase + i];
            int s = src[tileBase + i];
            bk[k] = d >> BSHIFT;
            pk[k] = (s << BSHIFT) | (d & (BNODES - 1));
            atomicAdd(&cnt[bk[k]], 1);
        } else bk[k] = -1;
    }
    __syncthreads();
    a[t] = cnt[t];
    __syncthreads();
    for (int off = 1; off < NBP; off <<= 1) {
        int v = (t >= off) ? a[t - off] : 0;
        __syncthreads();
        a[t] += v;
        __syncthreads();
    }
    base[t] = a[t] - cnt[t];
    lcur[t] = base[t];
    if (t < NB && cnt[t] > 0)
        gdelta[t] = atomicAdd(&bucketCur[t], cnt[t]) - base[t];
    __syncthreads();
#pragma unroll
    for (int k = 0; k < EPT; ++k) {
        if (bk[k] >= 0) {
            int l = atomicAdd(&lcur[bk[k]], 1);
            sorted[l] = pk[k];
            sdelta[l] = gdelta[bk[k]];
        }
    }
    __syncthreads();
    for (int i = t; i < tileCnt; i += 256)
        packed[i + sdelta[i]] = sorted[i];
}

// one WG per bucket: per-node histogram -> rowptr + dinv, then local col scatter
__global__ __launch_bounds__(512) void k_bucket_csr(
        const int* __restrict__ packed, const int* __restrict__ bucketBase,
        int* __restrict__ rowptr, int* __restrict__ col, float* __restrict__ dinv,
        int n, int e) {
    __shared__ int hist[BNODES], a[BNODES], cur[BNODES];
    int b = blockIdx.x;
    int node0 = b * BNODES;
    int nn = min(BNODES, n - node0);
    int eb = bucketBase[b], ee = bucketBase[b + 1];
    int t = threadIdx.x;  // 512 threads
    hist[t] = 0;
    __syncthreads();
    for (int i = eb + t; i < ee; i += 512)
        atomicAdd(&hist[packed[i] & (BNODES - 1)], 1);
    __syncthreads();
    a[t] = hist[t];
    __syncthreads();
    for (int off = 1; off < BNODES; off <<= 1) {
        int v = (t >= off) ? a[t - off] : 0;
        __syncthreads();
        a[t] += v;
        __syncthreads();
    }
    int excl = a[t] - hist[t];
    cur[t] = excl;
    if (t < nn) {
        rowptr[node0 + t] = eb + excl;
        dinv[node0 + t] = rsqrtf((float)(1 + hist[t]));
    }
    if (b == gridDim.x - 1 && t == 0) rowptr[n] = e;
    __syncthreads();
    for (int i = eb + t; i < ee; i += 512) {
        int p = packed[i];
        int dl = p & (BNODES - 1);
        int l = atomicAdd(&cur[dl], 1);
        col[eb + l] = p >> BSHIFT;
    }
}

// ---------------- fp16 prep ----------------

// U[n][32] = fp16(dinv[n] * X[n][k]); idx over n*8 float4s
__global__ void k_prescale(const float* __restrict__ X, const float* __restrict__ dinv,
                           _Float16* __restrict__ U, int n) {
    int idx = blockIdx.x * blockDim.x + threadIdx.x;
    if (idx >= n * 8) return;
    int node = idx >> 3;
    float4 v = ((const float4*)X)[idx];
    float di = dinv[node];
    half4 h;
    h[0] = (_Float16)(v.x * di);
    h[1] = (_Float16)(v.y * di);
    h[2] = (_Float16)(v.z * di);
    h[3] = (_Float16)(v.w * di);
    ((half4*)U)[idx] = h;
}

// Pack W [K][64] f32 into MFMA B-frag order, fp16:
// Wp[(((ks*4)+cb)*64 + lane)*8 + j] = W[ks*32 + (lane>>4)*8 + j][cb*16 + (lane&15)]
__global__ void k_packW(const float* __restrict__ W1, _Float16* __restrict__ Wp1,
                        const float* __restrict__ W2, _Float16* __restrict__ Wp2) {
    const float* W = blockIdx.x ? W2 : W1;
    _Float16* Wp = blockIdx.x ? Wp2 : Wp1;
    int IC = blockIdx.x ? 64 : 32;
    int total = IC * 64;
    for (int idx = threadIdx.x; idx < total; idx += blockDim.x) {
        int j = idx & 7;
        int l = (idx >> 3) & 63;
        int cbks = idx >> 9;
        int cb = cbks & 3;
        int ks = cbks >> 2;
        int k = ks * 32 + (l >> 4) * 8 + j;
        int c = cb * 16 + (l & 15);
        Wp[idx] = (_Float16)W[k * 64 + c];
    }
}

// ---------------- gather (fp16 rows, f32 accum) ----------------

// agg[n] = fp16( dinv[n] * (G[n] + sum_{in-edges} G[src]) ), G pre-scaled by dinv
// LPN lanes per node, 8 fp16 (16B) per lane; IC = LPN*8 channels
template <int LPN>
__global__ void k_gatherh(const _Float16* __restrict__ G, const int* __restrict__ rowptr,
                          const int* __restrict__ col, const float* __restrict__ dinv,
                          _Float16* __restrict__ out, int n) {
    constexpr int RW = LPN;  // half8s per row
    int idx = blockIdx.x * blockDim.x + threadIdx.x;
    int node = idx / LPN;
    int l = idx % LPN;
    if (node >= n) return;
    const half8* Gr = (const half8*)G;
    half8 s = Gr[(size_t)node * RW + l];
    float acc[8];
#pragma unroll
    for (int q = 0; q < 8; ++q) acc[q] = (float)s[q];
    int jb = rowptr[node], je = rowptr[node + 1];
    int j = jb;
    for (; j + 1 < je; j += 2) {
        int s0 = col[j], s1 = col[j + 1];
        half8 v0 = Gr[(size_t)s0 * RW + l];
        half8 v1 = Gr[(size_t)s1 * RW + l];
#pragma unroll
        for (int q = 0; q < 8; ++q) acc[q] += (float)v0[q] + (float)v1[q];
    }
    if (j < je) {
        half8 v0 = Gr[(size_t)col[j] * RW + l];
#pragma unroll
        for (int q = 0; q < 8; ++q) acc[q] += (float)v0[q];
    }
    float di = dinv[node];
    half8 r;
#pragma unroll
    for (int q = 0; q < 8; ++q) r[q] = (_Float16)(acc[q] * di);
    ((half8*)out)[(size_t)node * RW + l] = r;
}

// ---------------- MFMA GEMM ----------------

// C[16 nodes][64 ch] per wave; A = fp16 node rows [n][IC]; Wp packed B-frags.
// epilogue: v = relu(acc + b[ch]); FP16OUT ? out=fp16(v*dinv[node]) : out=f32 v
template <int IC, bool FP16OUT>
__global__ __launch_bounds__(256) void k_gemm_mfma(
        const _Float16* __restrict__ A, const _Float16* __restrict__ Wp,
        const float* __restrict__ bias, const float* __restrict__ dinv,
        void* __restrict__ outv, int n) {
    constexpr int KS = IC / 32;
    const int lane = threadIdx.x & 63;
    const int w = threadIdx.x >> 6;
    int tile = blockIdx.x * 4 + w;
    int node0 = tile * 16;
    if (node0 >= n) return;

    half8 bf[KS][4];
#pragma unroll
    for (int ks = 0; ks < KS; ++ks)
#pragma unroll
        for (int cb = 0; cb < 4; ++cb)
            bf[ks][cb] = ((const half8*)Wp)[(ks * 4 + cb) * 64 + lane];

    const _Float16* Ar = A + (size_t)(node0 + (lane & 15)) * IC + (lane >> 4) * 8;
    half8 af[KS];
#pragma unroll
    for (int ks = 0; ks < KS; ++ks)
        af[ks] = *(const half8*)(Ar + ks * 32);

    floatx4 z = {0.f, 0.f, 0.f, 0.f};
    floatx4 acc[4] = {z, z, z, z};
#pragma unroll
    for (int ks = 0; ks < KS; ++ks)
#pragma unroll
        for (int cb = 0; cb < 4; ++cb)
            acc[cb] = __builtin_amdgcn_mfma_f32_16x16x32_f16(af[ks], bf[ks][cb], acc[cb], 0, 0, 0);

    int r0 = node0 + (lane >> 4) * 4;
    int ch0 = lane & 15;
    float di[4];
#pragma unroll
    for (int r = 0; r < 4; ++r) di[r] = FP16OUT ? dinv[r0 + r] : 0.f;
#pragma unroll
    for (int cb = 0; cb < 4; ++cb) {
        int ch = cb * 16 + ch0;
        float bb = bias[ch];
#pragma unroll
        for (int r = 0; r < 4; ++r) {
            float v = acc[cb][r] + bb;
            v = v > 0.f ? v : 0.f;
            if (FP16OUT)
                ((_Float16*)outv)[(size_t)(r0 + r) * 64 + ch] = (_Float16)(v * di[r]);
            else
                ((float*)outv)[(size_t)(r0 + r) * 64 + ch] = v;
        }
    }
}

// ---------------- launch ----------------

extern "C" void kernel_launch(void* const* d_in, const int* in_sizes, int n_in,
                              void* d_out, int out_size, void* d_ws, size_t ws_size,
                              hipStream_t stream) {
    const float* x  = (const float*)d_in[0];
    const int* ei   = (const int*)d_in[1];   // [2, E] row-major, int32
    const float* W1 = (const float*)d_in[2];
    const float* b1 = (const float*)d_in[3];
    const float* W2 = (const float*)d_in[4];
    const float* b2 = (const float*)d_in[5];

    const int N = N_NODES;
    const int E = N_EDGES;
    const int* src = ei;       // edge_index[0]
    const int* dst = ei + E;   // edge_index[1]

    // workspace layout (512B aligned blocks)
    char* ws = (char*)d_ws;
    size_t off = 0;
    auto alloc = [&](size_t bytes) { void* p = ws + off; off = (off + bytes + 511) & ~511ull; return p; };
    int*   bucketCnt  = (int*)  alloc((size_t)NB * 4);
    int*   bucketBase = (int*)  alloc((size_t)(NB + 1) * 4);
    int*   bucketCur  = (int*)  alloc((size_t)NB * 4);
    int*   packed     = (int*)  alloc((size_t)E * 4);
    int*   rowptr     = (int*)  alloc((size_t)(N + 1) * 4);
    int*   col        = (int*)  alloc((size_t)E * 4);
    float* dinv       = (float*)alloc((size_t)N * 4);
    _Float16* Wp1     = (_Float16*)alloc((size_t)32 * 64 * 2);
    _Float16* Wp2     = (_Float16*)alloc((size_t)64 * 64 * 2);
    // slabA: [xh1 (N*32) | agg1h (N*32)]; reused whole as agg2h (N*64)
    _Float16* slabA   = (_Float16*)alloc((size_t)N * 64 * 2);   // 12.8 MB
    _Float16* xh1     = slabA;
    _Float16* agg1h   = slabA + (size_t)N * 32;
    _Float16* agg2h   = slabA;
    _Float16* xh2     = (_Float16*)alloc((size_t)N * 64 * 2);   // 12.8 MB
    float* outF       = (float*)d_out;

    const int B = 256;
    const int nTiles = (E + TILE - 1) / TILE;        // 391
    const int nMfmaBlocks = (N / 16 + 3) / 4;        // 1563 (N % 16 == 0)

    // ---- CSR build ----
    hipMemsetAsync(bucketCnt, 0, (size_t)NB * 4, stream);
    k_hist<<<256, B, 0, stream>>>(dst, bucketCnt, E);
    k_bscan<<<1, NBP, 0, stream>>>(bucketCnt, bucketBase, bucketCur);
    k_redistribute<<<nTiles, B, 0, stream>>>(src, dst, bucketCur, packed, E);
    k_bucket_csr<<<NB, BNODES, 0, stream>>>(packed, bucketBase, rowptr, col, dinv, N, E);

    // ---- prep ----
    k_packW<<<2, B, 0, stream>>>(W1, Wp1, W2, Wp2);
    k_prescale<<<(N * 8 + B - 1) / B, B, 0, stream>>>(x, dinv, xh1, N);

    // ---- layer 1: aggregate (32ch) then transform ----
    k_gatherh<4><<<((size_t)N * 4 + B - 1) / B, B, 0, stream>>>(xh1, rowptr, col, dinv, agg1h, N);
    k_gemm_mfma<32, true><<<nMfmaBlocks, B, 0, stream>>>(agg1h, Wp1, b1, dinv, xh2, N);

    // ---- layer 2: aggregate (64ch) then transform ----
    k_gatherh<8><<<((size_t)N * 8 + B - 1) / B, B, 0, stream>>>(xh2, rowptr, col, dinv, agg2h, N);
    k_gemm_mfma<64, false><<<nMfmaBlocks, B, 0, stream>>>(agg2h, Wp2, b2, dinv, outF, N);
}

// Round 6
// 127.855 us; speedup vs baseline: 7.3680x; 1.0723x over previous
//
#include <hip/hip_runtime.h>

#define N_NODES 100000
#define N_EDGES 1600000
#define BSHIFT 9
#define BNODES 512                                  // nodes per bucket (2^BSHIFT)
#define NB ((N_NODES + BNODES - 1) / BNODES)        // 196 buckets
#define NBP 256                                     // padded for scans
#define NHB 256                                     // histogram blocks
#define TILE 4096
#define EPT 16                                      // edges/thread in redistribute (256 thr)

typedef _Float16 half8 __attribute__((ext_vector_type(8)));
typedef _Float16 half4 __attribute__((ext_vector_type(4)));
typedef float floatx4 __attribute__((ext_vector_type(4)));

// ---------------- CSR build (bucketed counting sort) ----------------

// per-block partial histograms, no global atomics, no zero-init of global needed
__global__ __launch_bounds__(256) void k_hist(const int* __restrict__ dst,
                                              int* __restrict__ partial, int e) {
    __shared__ int h[NBP];
    for (int i = threadIdx.x; i < NBP; i += 256) h[i] = 0;
    __syncthreads();
    int chunk = (e + NHB - 1) / NHB;
    int lo = blockIdx.x * chunk;
    int hi = min(e, lo + chunk);
    for (int i = lo + threadIdx.x; i < hi; i += 256)
        atomicAdd(&h[dst[i] >> BSHIFT], 1);
    __syncthreads();
    for (int i = threadIdx.x; i < NBP; i += 256)
        partial[blockIdx.x * NBP + i] = h[i];
}

__device__ void packW_dev(const float* __restrict__ W, _Float16* __restrict__ Wp, int IC) {
    int total = IC * 64;
    for (int idx = threadIdx.x; idx < total; idx += 256) {
        int j = idx & 7;
        int l = (idx >> 3) & 63;
        int cbks = idx >> 9;
        int cb = cbks & 3;
        int ks = cbks >> 2;
        int k = ks * 32 + (l >> 4) * 8 + j;
        int c = cb * 16 + (l & 15);
        Wp[idx] = (_Float16)W[k * 64 + c];
    }
}

// block 0: reduce partials + exclusive scan -> bucketBase/bucketCur
// blocks 1,2: pack W1/W2 into MFMA B-frag order (independent work, fused to save a launch)
__global__ __launch_bounds__(256) void k_bscan_pack(
        const int* __restrict__ partial, int* __restrict__ bucketBase, int* __restrict__ bucketCur,
        const float* __restrict__ W1, _Float16* __restrict__ Wp1,
        const float* __restrict__ W2, _Float16* __restrict__ Wp2) {
    if (blockIdx.x == 1) { packW_dev(W1, Wp1, 32); return; }
    if (blockIdx.x == 2) { packW_dev(W2, Wp2, 64); return; }
    __shared__ int a[NBP];
    int t = threadIdx.x;  // 256 threads
    int cnt = 0;
    for (int b = 0; b < NHB; ++b) cnt += partial[b * NBP + t];  // coalesced across t
    a[t] = cnt;
    __syncthreads();
    for (int off = 1; off < NBP; off <<= 1) {
        int v = (t >= off) ? a[t - off] : 0;
        __syncthreads();
        a[t] += v;
        __syncthreads();
    }
    if (t < NB) {
        int incl = a[t];
        int excl = incl - cnt;
        bucketBase[t] = excl;
        bucketCur[t] = excl;
        if (t == NB - 1) bucketBase[NB] = incl;
    }
}

// tile-local counting sort by bucket, then coalesced append into global packed[]
__global__ __launch_bounds__(256) void k_redistribute(
        const int* __restrict__ src, const int* __restrict__ dst,
        int* __restrict__ bucketCur, int* __restrict__ packed, int e) {
    __shared__ int cnt[NBP], base[NBP], gdelta[NBP], lcur[NBP], a[NBP];
    __shared__ int sorted[TILE];
    __shared__ int sdelta[TILE];
    int tileBase = blockIdx.x * TILE;
    int tileCnt = min(TILE, e - tileBase);
    int t = threadIdx.x;
    for (int i = t; i < NBP; i += 256) cnt[i] = 0;
    __syncthreads();
    int pk[EPT], bk[EPT];
#pragma unroll
    for (int k = 0; k < EPT; ++k) {
        int i = k * 256 + t;
        if (i < tileCnt) {
            int d = dst[tileBase + i];
            int s = src[tileBase + i];
            bk[k] = d >> BSHIFT;
            pk[k] = (s << BSHIFT) | (d & (BNODES - 1));
            atomicAdd(&cnt[bk[k]], 1);
        } else bk[k] = -1;
    }
    __syncthreads();
    a[t] = cnt[t];
    __syncthreads();
    for (int off = 1; off < NBP; off <<= 1) {
        int v = (t >= off) ? a[t - off] : 0;
        __syncthreads();
        a[t] += v;
        __syncthreads();
    }
    base[t] = a[t] - cnt[t];
    lcur[t] = base[t];
    if (t < NB && cnt[t] > 0)
        gdelta[t] = atomicAdd(&bucketCur[t], cnt[t]) - base[t];
    __syncthreads();
#pragma unroll
    for (int k = 0; k < EPT; ++k) {
        if (bk[k] >= 0) {
            int l = atomicAdd(&lcur[bk[k]], 1);
            sorted[l] = pk[k];
            sdelta[l] = gdelta[bk[k]];
        }
    }
    __syncthreads();
    for (int i = t; i < tileCnt; i += 256)
        packed[i + sdelta[i]] = sorted[i];
}

// one WG per bucket: per-node histogram -> rowptr + dinv, then local col scatter
__global__ __launch_bounds__(512) void k_bucket_csr(
        const int* __restrict__ packed, const int* __restrict__ bucketBase,
        int* __restrict__ rowptr, int* __restrict__ col, float* __restrict__ dinv,
        int n, int e) {
    __shared__ int hist[BNODES], a[BNODES], cur[BNODES];
    int b = blockIdx.x;
    int node0 = b * BNODES;
    int nn = min(BNODES, n - node0);
    int eb = bucketBase[b], ee = bucketBase[b + 1];
    int t = threadIdx.x;  // 512 threads
    hist[t] = 0;
    __syncthreads();
    for (int i = eb + t; i < ee; i += 512)
        atomicAdd(&hist[packed[i] & (BNODES - 1)], 1);
    __syncthreads();
    a[t] = hist[t];
    __syncthreads();
    for (int off = 1; off < BNODES; off <<= 1) {
        int v = (t >= off) ? a[t - off] : 0;
        __syncthreads();
        a[t] += v;
        __syncthreads();
    }
    int excl = a[t] - hist[t];
    cur[t] = excl;
    if (t < nn) {
        rowptr[node0 + t] = eb + excl;
        dinv[node0 + t] = rsqrtf((float)(1 + hist[t]));
    }
    if (b == gridDim.x - 1 && t == 0) rowptr[n] = e;
    __syncthreads();
    for (int i = eb + t; i < ee; i += 512) {
        int p = packed[i];
        int dl = p & (BNODES - 1);
        int l = atomicAdd(&cur[dl], 1);
        col[eb + l] = p >> BSHIFT;
    }
}

// ---------------- fp16 prep ----------------

// U[n][32] = fp16(dinv[n] * X[n][k]); idx over n*8 float4s
__global__ void k_prescale(const float* __restrict__ X, const float* __restrict__ dinv,
                           _Float16* __restrict__ U, int n) {
    int idx = blockIdx.x * blockDim.x + threadIdx.x;
    if (idx >= n * 8) return;
    int node = idx >> 3;
    float4 v = ((const float4*)X)[idx];
    float di = dinv[node];
    half4 h;
    h[0] = (_Float16)(v.x * di);
    h[1] = (_Float16)(v.y * di);
    h[2] = (_Float16)(v.z * di);
    h[3] = (_Float16)(v.w * di);
    ((half4*)U)[idx] = h;
}

// ---------------- gather (fp16 rows, f32 accum) ----------------

// agg[n] = fp16( dinv[n] * (G[n] + sum_{in-edges} G[src]) ), G pre-scaled by dinv
// LPN lanes per node, 8 fp16 (16B) per lane; IC = LPN*8 channels
template <int LPN>
__global__ void k_gatherh(const _Float16* __restrict__ G, const int* __restrict__ rowptr,
                          const int* __restrict__ col, const float* __restrict__ dinv,
                          _Float16* __restrict__ out, int n) {
    constexpr int RW = LPN;  // half8s per row
    int idx = blockIdx.x * blockDim.x + threadIdx.x;
    int node = idx / LPN;
    int l = idx % LPN;
    if (node >= n) return;
    const half8* Gr = (const half8*)G;
    half8 s = Gr[(size_t)node * RW + l];
    float acc[8];
#pragma unroll
    for (int q = 0; q < 8; ++q) acc[q] = (float)s[q];
    int jb = rowptr[node], je = rowptr[node + 1];
    int j = jb;
    for (; j + 3 < je; j += 4) {  // unroll-4: 4 col + 4 row loads in flight
        int s0 = col[j], s1 = col[j + 1], s2 = col[j + 2], s3 = col[j + 3];
        half8 v0 = Gr[(size_t)s0 * RW + l];
        half8 v1 = Gr[(size_t)s1 * RW + l];
        half8 v2 = Gr[(size_t)s2 * RW + l];
        half8 v3 = Gr[(size_t)s3 * RW + l];
#pragma unroll
        for (int q = 0; q < 8; ++q)
            acc[q] += ((float)v0[q] + (float)v1[q]) + ((float)v2[q] + (float)v3[q]);
    }
    for (; j < je; ++j) {
        half8 v0 = Gr[(size_t)col[j] * RW + l];
#pragma unroll
        for (int q = 0; q < 8; ++q) acc[q] += (float)v0[q];
    }
    float di = dinv[node];
    half8 r;
#pragma unroll
    for (int q = 0; q < 8; ++q) r[q] = (_Float16)(acc[q] * di);
    ((half8*)out)[(size_t)node * RW + l] = r;
}

// ---------------- MFMA GEMM ----------------

// C[16 nodes][64 ch] per wave; A = fp16 node rows [n][IC]; Wp packed B-frags.
// epilogue: v = relu(acc + b[ch]); FP16OUT ? out=fp16(v*dinv[node]) : out=f32 v
template <int IC, bool FP16OUT>
__global__ __launch_bounds__(256) void k_gemm_mfma(
        const _Float16* __restrict__ A, const _Float16* __restrict__ Wp,
        const float* __restrict__ bias, const float* __restrict__ dinv,
        void* __restrict__ outv, int n) {
    constexpr int KS = IC / 32;
    const int lane = threadIdx.x & 63;
    const int w = threadIdx.x >> 6;
    int tile = blockIdx.x * 4 + w;
    int node0 = tile * 16;
    if (node0 >= n) return;

    half8 bf[KS][4];
#pragma unroll
    for (int ks = 0; ks < KS; ++ks)
#pragma unroll
        for (int cb = 0; cb < 4; ++cb)
            bf[ks][cb] = ((const half8*)Wp)[(ks * 4 + cb) * 64 + lane];

    const _Float16* Ar = A + (size_t)(node0 + (lane & 15)) * IC + (lane >> 4) * 8;
    half8 af[KS];
#pragma unroll
    for (int ks = 0; ks < KS; ++ks)
        af[ks] = *(const half8*)(Ar + ks * 32);

    floatx4 z = {0.f, 0.f, 0.f, 0.f};
    floatx4 acc[4] = {z, z, z, z};
#pragma unroll
    for (int ks = 0; ks < KS; ++ks)
#pragma unroll
        for (int cb = 0; cb < 4; ++cb)
            acc[cb] = __builtin_amdgcn_mfma_f32_16x16x32_f16(af[ks], bf[ks][cb], acc[cb], 0, 0, 0);

    int r0 = node0 + (lane >> 4) * 4;
    int ch0 = lane & 15;
    float di[4];
#pragma unroll
    for (int r = 0; r < 4; ++r) di[r] = FP16OUT ? dinv[r0 + r] : 0.f;
#pragma unroll
    for (int cb = 0; cb < 4; ++cb) {
        int ch = cb * 16 + ch0;
        float bb = bias[ch];
#pragma unroll
        for (int r = 0; r < 4; ++r) {
            float v = acc[cb][r] + bb;
            v = v > 0.f ? v : 0.f;
            if (FP16OUT)
                ((_Float16*)outv)[(size_t)(r0 + r) * 64 + ch] = (_Float16)(v * di[r]);
            else
                ((float*)outv)[(size_t)(r0 + r) * 64 + ch] = v;
        }
    }
}

// ---------------- launch ----------------

extern "C" void kernel_launch(void* const* d_in, const int* in_sizes, int n_in,
                              void* d_out, int out_size, void* d_ws, size_t ws_size,
                              hipStream_t stream) {
    const float* x  = (const float*)d_in[0];
    const int* ei   = (const int*)d_in[1];   // [2, E] row-major, int32
    const float* W1 = (const float*)d_in[2];
    const float* b1 = (const float*)d_in[3];
    const float* W2 = (const float*)d_in[4];
    const float* b2 = (const float*)d_in[5];

    const int N = N_NODES;
    const int E = N_EDGES;
    const int* src = ei;       // edge_index[0]
    const int* dst = ei + E;   // edge_index[1]

    // workspace layout (512B aligned blocks)
    char* ws = (char*)d_ws;
    size_t off = 0;
    auto alloc = [&](size_t bytes) { void* p = ws + off; off = (off + bytes + 511) & ~511ull; return p; };
    int*   partial    = (int*)  alloc((size_t)NHB * NBP * 4);   // 256 KB
    int*   bucketBase = (int*)  alloc((size_t)(NB + 1) * 4);
    int*   bucketCur  = (int*)  alloc((size_t)NB * 4);
    int*   packed     = (int*)  alloc((size_t)E * 4);
    int*   rowptr     = (int*)  alloc((size_t)(N + 1) * 4);
    int*   col        = (int*)  alloc((size_t)E * 4);
    float* dinv       = (float*)alloc((size_t)N * 4);
    _Float16* Wp1     = (_Float16*)alloc((size_t)32 * 64 * 2);
    _Float16* Wp2     = (_Float16*)alloc((size_t)64 * 64 * 2);
    // slabA: [xh1 (N*32) | agg1h (N*32)]; reused whole as agg2h (N*64)
    _Float16* slabA   = (_Float16*)alloc((size_t)N * 64 * 2);   // 12.8 MB
    _Float16* xh1     = slabA;
    _Float16* agg1h   = slabA + (size_t)N * 32;
    _Float16* agg2h   = slabA;
    _Float16* xh2     = (_Float16*)alloc((size_t)N * 64 * 2);   // 12.8 MB
    float* outF       = (float*)d_out;

    const int B = 256;
    const int nTiles = (E + TILE - 1) / TILE;        // 391
    const int nMfmaBlocks = (N / 16 + 3) / 4;        // 1563 (N % 16 == 0)

    // ---- CSR build (no memset: partial histograms) ----
    k_hist<<<NHB, B, 0, stream>>>(dst, partial, E);
    k_bscan_pack<<<3, B, 0, stream>>>(partial, bucketBase, bucketCur, W1, Wp1, W2, Wp2);
    k_redistribute<<<nTiles, B, 0, stream>>>(src, dst, bucketCur, packed, E);
    k_bucket_csr<<<NB, BNODES, 0, stream>>>(packed, bucketBase, rowptr, col, dinv, N, E);

    // ---- prep ----
    k_prescale<<<(N * 8 + B - 1) / B, B, 0, stream>>>(x, dinv, xh1, N);

    // ---- layer 1: aggregate (32ch) then transform ----
    k_gatherh<4><<<((size_t)N * 4 + B - 1) / B, B, 0, stream>>>(xh1, rowptr, col, dinv, agg1h, N);
    k_gemm_mfma<32, true><<<nMfmaBlocks, B, 0, stream>>>(agg1h, Wp1, b1, dinv, xh2, N);

    // ---- layer 2: aggregate (64ch) then transform ----
    k_gatherh<8><<<((size_t)N * 8 + B - 1) / B, B, 0, stream>>>(xh2, rowptr, col, dinv, agg2h, N);
    k_gemm_mfma<64, false><<<nMfmaBlocks, B, 0, stream>>>(agg2h, Wp2, b2, dinv, outF, N);
}

// Round 7
// 122.767 us; speedup vs baseline: 7.6734x; 1.0414x over previous
//
#include <hip/hip_runtime.h>

#define N_NODES 100000
#define N_EDGES 1600000
#define BSHIFT 9
#define BNODES 512                                  // nodes per bucket (2^BSHIFT)
#define NB ((N_NODES + BNODES - 1) / BNODES)        // 196 buckets
#define NBP 256                                     // padded for scans
#define NHB 256                                     // histogram blocks
#define TILE 4096
#define EPT 16                                      // edges/thread in redistribute (256 thr)

typedef _Float16 half8 __attribute__((ext_vector_type(8)));
typedef _Float16 half4 __attribute__((ext_vector_type(4)));
typedef float floatx4 __attribute__((ext_vector_type(4)));

// ---------------- CSR build (bucketed counting sort) ----------------

// per-block partial histograms, no global atomics, no zero-init of global needed
__global__ __launch_bounds__(256) void k_hist(const int* __restrict__ dst,
                                              int* __restrict__ partial, int e) {
    __shared__ int h[NBP];
    for (int i = threadIdx.x; i < NBP; i += 256) h[i] = 0;
    __syncthreads();
    int chunk = (e + NHB - 1) / NHB;
    int lo = blockIdx.x * chunk;
    int hi = min(e, lo + chunk);
    for (int i = lo + threadIdx.x; i < hi; i += 256)
        atomicAdd(&h[dst[i] >> BSHIFT], 1);
    __syncthreads();
    for (int i = threadIdx.x; i < NBP; i += 256)
        partial[blockIdx.x * NBP + i] = h[i];
}

__device__ void packW_dev(const float* __restrict__ W, _Float16* __restrict__ Wp, int IC) {
    int total = IC * 64;
    for (int idx = threadIdx.x; idx < total; idx += 256) {
        int j = idx & 7;
        int l = (idx >> 3) & 63;
        int cbks = idx >> 9;
        int cb = cbks & 3;
        int ks = cbks >> 2;
        int k = ks * 32 + (l >> 4) * 8 + j;
        int c = cb * 16 + (l & 15);
        Wp[idx] = (_Float16)W[k * 64 + c];
    }
}

// block 0: reduce partials + exclusive scan -> bucketBase/bucketCur
// blocks 1,2: pack W1/W2 into MFMA B-frag order (independent work, fused to save a launch)
__global__ __launch_bounds__(256) void k_bscan_pack(
        const int* __restrict__ partial, int* __restrict__ bucketBase, int* __restrict__ bucketCur,
        const float* __restrict__ W1, _Float16* __restrict__ Wp1,
        const float* __restrict__ W2, _Float16* __restrict__ Wp2) {
    if (blockIdx.x == 1) { packW_dev(W1, Wp1, 32); return; }
    if (blockIdx.x == 2) { packW_dev(W2, Wp2, 64); return; }
    __shared__ int a[NBP];
    int t = threadIdx.x;  // 256 threads
    int cnt = 0;
    for (int b = 0; b < NHB; ++b) cnt += partial[b * NBP + t];  // coalesced across t
    a[t] = cnt;
    __syncthreads();
    for (int off = 1; off < NBP; off <<= 1) {
        int v = (t >= off) ? a[t - off] : 0;
        __syncthreads();
        a[t] += v;
        __syncthreads();
    }
    if (t < NB) {
        int incl = a[t];
        int excl = incl - cnt;
        bucketBase[t] = excl;
        bucketCur[t] = excl;
        if (t == NB - 1) bucketBase[NB] = incl;
    }
}

// tile-local counting sort by bucket, then coalesced append into global packed[]
__global__ __launch_bounds__(256) void k_redistribute(
        const int* __restrict__ src, const int* __restrict__ dst,
        int* __restrict__ bucketCur, int* __restrict__ packed, int e) {
    __shared__ int cnt[NBP], base[NBP], gdelta[NBP], lcur[NBP], a[NBP];
    __shared__ int sorted[TILE];
    __shared__ int sdelta[TILE];
    int tileBase = blockIdx.x * TILE;
    int tileCnt = min(TILE, e - tileBase);
    int t = threadIdx.x;
    for (int i = t; i < NBP; i += 256) cnt[i] = 0;
    __syncthreads();
    int pk[EPT], bk[EPT];
#pragma unroll
    for (int k = 0; k < EPT; ++k) {
        int i = k * 256 + t;
        if (i < tileCnt) {
            int d = dst[tileBase + i];
            int s = src[tileBase + i];
            bk[k] = d >> BSHIFT;
            pk[k] = (s << BSHIFT) | (d & (BNODES - 1));
            atomicAdd(&cnt[bk[k]], 1);
        } else bk[k] = -1;
    }
    __syncthreads();
    a[t] = cnt[t];
    __syncthreads();
    for (int off = 1; off < NBP; off <<= 1) {
        int v = (t >= off) ? a[t - off] : 0;
        __syncthreads();
        a[t] += v;
        __syncthreads();
    }
    base[t] = a[t] - cnt[t];
    lcur[t] = base[t];
    if (t < NB && cnt[t] > 0)
        gdelta[t] = atomicAdd(&bucketCur[t], cnt[t]) - base[t];
    __syncthreads();
#pragma unroll
    for (int k = 0; k < EPT; ++k) {
        if (bk[k] >= 0) {
            int l = atomicAdd(&lcur[bk[k]], 1);
            sorted[l] = pk[k];
            sdelta[l] = gdelta[bk[k]];
        }
    }
    __syncthreads();
    for (int i = t; i < tileCnt; i += 256)
        packed[i + sdelta[i]] = sorted[i];
}

// one WG per bucket: per-node histogram -> rowptr + dinv, local col scatter,
// FUSED: fp16 prescale of this bucket's x rows (xh1 = fp16(dinv * x))
__global__ __launch_bounds__(512) void k_bucket_csr(
        const int* __restrict__ packed, const int* __restrict__ bucketBase,
        int* __restrict__ rowptr, int* __restrict__ col, float* __restrict__ dinv,
        const float* __restrict__ X, _Float16* __restrict__ xh1,
        int n, int e) {
    __shared__ int hist[BNODES], a[BNODES], cur[BNODES];
    __shared__ float dinvS[BNODES];
    int b = blockIdx.x;
    int node0 = b * BNODES;
    int nn = min(BNODES, n - node0);
    int eb = bucketBase[b], ee = bucketBase[b + 1];
    int t = threadIdx.x;  // 512 threads
    hist[t] = 0;
    __syncthreads();
    for (int i = eb + t; i < ee; i += 512)
        atomicAdd(&hist[packed[i] & (BNODES - 1)], 1);
    __syncthreads();
    a[t] = hist[t];
    __syncthreads();
    for (int off = 1; off < BNODES; off <<= 1) {
        int v = (t >= off) ? a[t - off] : 0;
        __syncthreads();
        a[t] += v;
        __syncthreads();
    }
    int excl = a[t] - hist[t];
    cur[t] = excl;
    float di = rsqrtf((float)(1 + hist[t]));
    dinvS[t] = di;
    if (t < nn) {
        rowptr[node0 + t] = eb + excl;
        dinv[node0 + t] = di;
    }
    if (b == gridDim.x - 1 && t == 0) rowptr[n] = e;
    __syncthreads();
    // col scatter (32KB L2-local region)
    for (int i = eb + t; i < ee; i += 512) {
        int p = packed[i];
        int dl = p & (BNODES - 1);
        int l = atomicAdd(&cur[dl], 1);
        col[eb + l] = p >> BSHIFT;
    }
    // fused prescale: xh1[node] = fp16(dinv[node] * x[node]), 8 float4 per row
    const float4* X4 = (const float4*)X;
    half4* U4 = (half4*)xh1;
    for (int i = t; i < nn * 8; i += 512) {
        int nl = i >> 3;
        float4 v = X4[(size_t)(node0 + nl) * 8 + (i & 7)];
        float d2 = dinvS[nl];
        half4 h;
        h[0] = (_Float16)(v.x * d2);
        h[1] = (_Float16)(v.y * d2);
        h[2] = (_Float16)(v.z * d2);
        h[3] = (_Float16)(v.w * d2);
        U4[(size_t)(node0 + nl) * 8 + (i & 7)] = h;
    }
}

// ---------------- fused gather + MFMA GEMM layers ----------------
// Block = 256 threads = 64 nodes. Phase 1: gather agg rows into LDS (fp16,
// padded stride vs bank conflicts). Phase 2: 4 waves x 16-node MFMA tiles.

// Layer 1: IC=32 (4 half8/row), OC=64, out = fp16(dinv * relu(agg@W1 + b1))
__global__ __launch_bounds__(256) void k_fused1(
        const _Float16* __restrict__ G, const int* __restrict__ rowptr,
        const int* __restrict__ col, const float* __restrict__ dinv,
        const _Float16* __restrict__ Wp, const float* __restrict__ bias,
        _Float16* __restrict__ out, int n) {
    __shared__ _Float16 aggS[64][40];   // stride 40 fp16 = 80B -> 2-way banks
    const int t = threadIdx.x;
    const int node0 = blockIdx.x * 64;
    {   // gather: 4 threads/node, 1 half8 each
        int nl = t >> 2, l = t & 3;
        int node = node0 + nl;
        if (node < n) {
            const half8* Gr = (const half8*)G;  // 4 half8 per 32ch row
            half8 s = Gr[(size_t)node * 4 + l];
            float acc[8];
#pragma unroll
            for (int q = 0; q < 8; ++q) acc[q] = (float)s[q];
            int jb = rowptr[node], je = rowptr[node + 1];
            int j = jb;
            for (; j + 3 < je; j += 4) {
                int s0 = col[j], s1 = col[j + 1], s2 = col[j + 2], s3 = col[j + 3];
                half8 v0 = Gr[(size_t)s0 * 4 + l];
                half8 v1 = Gr[(size_t)s1 * 4 + l];
                half8 v2 = Gr[(size_t)s2 * 4 + l];
                half8 v3 = Gr[(size_t)s3 * 4 + l];
#pragma unroll
                for (int q = 0; q < 8; ++q)
                    acc[q] += ((float)v0[q] + (float)v1[q]) + ((float)v2[q] + (float)v3[q]);
            }
            for (; j < je; ++j) {
                half8 v0 = Gr[(size_t)col[j] * 4 + l];
#pragma unroll
                for (int q = 0; q < 8; ++q) acc[q] += (float)v0[q];
            }
            float di = dinv[node];
            half8 r;
#pragma unroll
            for (int q = 0; q < 8; ++q) r[q] = (_Float16)(acc[q] * di);
            *(half8*)&aggS[nl][l * 8] = r;
        }
    }
    __syncthreads();
    {   // MFMA: wave w -> nodes node0 + w*16 .. +15  (n % 16 == 0)
        const int lane = t & 63;
        const int w = t >> 6;
        int base = w * 16;
        int nw0 = node0 + base;
        if (nw0 >= n) return;
        half8 af = *(const half8*)&aggS[base + (lane & 15)][(lane >> 4) * 8];
        floatx4 z = {0.f, 0.f, 0.f, 0.f};
        floatx4 acc[4] = {z, z, z, z};
#pragma unroll
        for (int cb = 0; cb < 4; ++cb) {
            half8 bf = ((const half8*)Wp)[cb * 64 + lane];
            acc[cb] = __builtin_amdgcn_mfma_f32_16x16x32_f16(af, bf, acc[cb], 0, 0, 0);
        }
        int r0 = nw0 + (lane >> 4) * 4;
        int ch0 = lane & 15;
        float di[4];
#pragma unroll
        for (int r = 0; r < 4; ++r) di[r] = dinv[r0 + r];
#pragma unroll
        for (int cb = 0; cb < 4; ++cb) {
            int ch = cb * 16 + ch0;
            float bb = bias[ch];
#pragma unroll
            for (int r = 0; r < 4; ++r) {
                float v = acc[cb][r] + bb;
                v = v > 0.f ? v : 0.f;
                out[(size_t)(r0 + r) * 64 + ch] = (_Float16)(v * di[r]);
            }
        }
    }
}

// Layer 2: IC=64 (8 half8/row), OC=64, out = f32 relu(agg@W2 + b2)
__global__ __launch_bounds__(256) void k_fused2(
        const _Float16* __restrict__ G, const int* __restrict__ rowptr,
        const int* __restrict__ col, const float* __restrict__ dinv,
        const _Float16* __restrict__ Wp, const float* __restrict__ bias,
        float* __restrict__ out, int n) {
    __shared__ _Float16 aggS[64][72];   // stride 72 fp16 = 144B -> 2-way banks
    const int t = threadIdx.x;
    const int node0 = blockIdx.x * 64;
    {   // gather: 4 threads/node, 2 half8 each
        int nl = t >> 2, l2 = (t & 3) * 2;
        int node = node0 + nl;
        if (node < n) {
            const half8* Gr = (const half8*)G;  // 8 half8 per 64ch row
            half8 sA = Gr[(size_t)node * 8 + l2];
            half8 sB = Gr[(size_t)node * 8 + l2 + 1];
            float accA[8], accB[8];
#pragma unroll
            for (int q = 0; q < 8; ++q) { accA[q] = (float)sA[q]; accB[q] = (float)sB[q]; }
            int jb = rowptr[node], je = rowptr[node + 1];
            int j = jb;
            for (; j + 1 < je; j += 2) {
                int s0 = col[j], s1 = col[j + 1];
                half8 a0 = Gr[(size_t)s0 * 8 + l2];
                half8 b0 = Gr[(size_t)s0 * 8 + l2 + 1];
                half8 a1 = Gr[(size_t)s1 * 8 + l2];
                half8 b1 = Gr[(size_t)s1 * 8 + l2 + 1];
#pragma unroll
                for (int q = 0; q < 8; ++q) {
                    accA[q] += (float)a0[q] + (float)a1[q];
                    accB[q] += (float)b0[q] + (float)b1[q];
                }
            }
            if (j < je) {
                int s0 = col[j];
                half8 a0 = Gr[(size_t)s0 * 8 + l2];
                half8 b0 = Gr[(size_t)s0 * 8 + l2 + 1];
#pragma unroll
                for (int q = 0; q < 8; ++q) { accA[q] += (float)a0[q]; accB[q] += (float)b0[q]; }
            }
            float di = dinv[node];
            half8 rA, rB;
#pragma unroll
            for (int q = 0; q < 8; ++q) {
                rA[q] = (_Float16)(accA[q] * di);
                rB[q] = (_Float16)(accB[q] * di);
            }
            *(half8*)&aggS[nl][l2 * 8] = rA;
            *(half8*)&aggS[nl][l2 * 8 + 8] = rB;
        }
    }
    __syncthreads();
    {   // MFMA: KS=2
        const int lane = t & 63;
        const int w = t >> 6;
        int base = w * 16;
        int nw0 = node0 + base;
        if (nw0 >= n) return;
        half8 af0 = *(const half8*)&aggS[base + (lane & 15)][(lane >> 4) * 8];
        half8 af1 = *(const half8*)&aggS[base + (lane & 15)][(lane >> 4) * 8 + 32];
        floatx4 z = {0.f, 0.f, 0.f, 0.f};
        floatx4 acc[4] = {z, z, z, z};
#pragma unroll
        for (int cb = 0; cb < 4; ++cb) {
            half8 bf0 = ((const half8*)Wp)[(0 * 4 + cb) * 64 + lane];
            half8 bf1 = ((const half8*)Wp)[(1 * 4 + cb) * 64 + lane];
            acc[cb] = __builtin_amdgcn_mfma_f32_16x16x32_f16(af0, bf0, acc[cb], 0, 0, 0);
            acc[cb] = __builtin_amdgcn_mfma_f32_16x16x32_f16(af1, bf1, acc[cb], 0, 0, 0);
        }
        int r0 = nw0 + (lane >> 4) * 4;
        int ch0 = lane & 15;
#pragma unroll
        for (int cb = 0; cb < 4; ++cb) {
            int ch = cb * 16 + ch0;
            float bb = bias[ch];
#pragma unroll
            for (int r = 0; r < 4; ++r) {
                float v = acc[cb][r] + bb;
                out[(size_t)(r0 + r) * 64 + ch] = v > 0.f ? v : 0.f;
            }
        }
    }
}

// ---------------- launch ----------------

extern "C" void kernel_launch(void* const* d_in, const int* in_sizes, int n_in,
                              void* d_out, int out_size, void* d_ws, size_t ws_size,
                              hipStream_t stream) {
    const float* x  = (const float*)d_in[0];
    const int* ei   = (const int*)d_in[1];   // [2, E] row-major, int32
    const float* W1 = (const float*)d_in[2];
    const float* b1 = (const float*)d_in[3];
    const float* W2 = (const float*)d_in[4];
    const float* b2 = (const float*)d_in[5];

    const int N = N_NODES;
    const int E = N_EDGES;
    const int* src = ei;       // edge_index[0]
    const int* dst = ei + E;   // edge_index[1]

    // workspace layout (512B aligned blocks)
    char* ws = (char*)d_ws;
    size_t off = 0;
    auto alloc = [&](size_t bytes) { void* p = ws + off; off = (off + bytes + 511) & ~511ull; return p; };
    int*   partial    = (int*)  alloc((size_t)NHB * NBP * 4);   // 256 KB
    int*   bucketBase = (int*)  alloc((size_t)(NB + 1) * 4);
    int*   bucketCur  = (int*)  alloc((size_t)NB * 4);
    int*   packed     = (int*)  alloc((size_t)E * 4);
    int*   rowptr     = (int*)  alloc((size_t)(N + 1) * 4);
    int*   col        = (int*)  alloc((size_t)E * 4);
    float* dinv       = (float*)alloc((size_t)N * 4);
    _Float16* Wp1     = (_Float16*)alloc((size_t)32 * 64 * 2);
    _Float16* Wp2     = (_Float16*)alloc((size_t)64 * 64 * 2);
    _Float16* xh1     = (_Float16*)alloc((size_t)N * 32 * 2);   // 6.4 MB
    _Float16* xh2     = (_Float16*)alloc((size_t)N * 64 * 2);   // 12.8 MB
    float* outF       = (float*)d_out;

    const int B = 256;
    const int nTiles = (E + TILE - 1) / TILE;        // 391
    const int nFBlocks = (N + 63) / 64;              // 1563

    // ---- CSR build ----
    k_hist<<<NHB, B, 0, stream>>>(dst, partial, E);
    k_bscan_pack<<<3, B, 0, stream>>>(partial, bucketBase, bucketCur, W1, Wp1, W2, Wp2);
    k_redistribute<<<nTiles, B, 0, stream>>>(src, dst, bucketCur, packed, E);
    k_bucket_csr<<<NB, BNODES, 0, stream>>>(packed, bucketBase, rowptr, col, dinv, x, xh1, N, E);

    // ---- layer 1 (gather 32ch + MFMA fused) ----
    k_fused1<<<nFBlocks, B, 0, stream>>>(xh1, rowptr, col, dinv, Wp1, b1, xh2, N);

    // ---- layer 2 (gather 64ch + MFMA fused) ----
    k_fused2<<<nFBlocks, B, 0, stream>>>(xh2, rowptr, col, dinv, Wp2, b2, outF, N);
}

// Round 8
// 117.625 us; speedup vs baseline: 8.0088x; 1.0437x over previous
//
#include <hip/hip_runtime.h>

#define N_NODES 100000
#define N_EDGES 1600000
#define BSHIFT 9
#define BNODES 512                                  // nodes per bucket (2^BSHIFT)
#define NB ((N_NODES + BNODES - 1) / BNODES)        // 196 buckets
#define NBP 256                                     // padded for scans
#define NHB 256                                     // histogram blocks
#define TILE 4096
#define EPT 16                                      // edges/thread in redistribute (256 thr)

typedef _Float16 half8 __attribute__((ext_vector_type(8)));
typedef _Float16 half4 __attribute__((ext_vector_type(4)));
typedef float floatx4 __attribute__((ext_vector_type(4)));

// ---------------- CSR build (bucketed counting sort) ----------------

// per-block partial histograms, no global atomics, no zero-init of global needed
__global__ __launch_bounds__(256) void k_hist(const int* __restrict__ dst,
                                              int* __restrict__ partial, int e) {
    __shared__ int h[NBP];
    for (int i = threadIdx.x; i < NBP; i += 256) h[i] = 0;
    __syncthreads();
    int chunk = (e + NHB - 1) / NHB;
    int lo = blockIdx.x * chunk;
    int hi = min(e, lo + chunk);
    for (int i = lo + threadIdx.x; i < hi; i += 256)
        atomicAdd(&h[dst[i] >> BSHIFT], 1);
    __syncthreads();
    for (int i = threadIdx.x; i < NBP; i += 256)
        partial[blockIdx.x * NBP + i] = h[i];
}

__device__ void packW_dev(const float* __restrict__ W, _Float16* __restrict__ Wp, int IC) {
    int total = IC * 64;
    for (int idx = threadIdx.x; idx < total; idx += 256) {
        int j = idx & 7;
        int l = (idx >> 3) & 63;
        int cbks = idx >> 9;
        int cb = cbks & 3;
        int ks = cbks >> 2;
        int k = ks * 32 + (l >> 4) * 8 + j;
        int c = cb * 16 + (l & 15);
        Wp[idx] = (_Float16)W[k * 64 + c];
    }
}

// block 0: reduce partials + exclusive scan -> bucketBase/bucketCur
// blocks 1,2: pack W1/W2 into MFMA B-frag order (independent work, fused to save a launch)
__global__ __launch_bounds__(256) void k_bscan_pack(
        const int* __restrict__ partial, int* __restrict__ bucketBase, int* __restrict__ bucketCur,
        const float* __restrict__ W1, _Float16* __restrict__ Wp1,
        const float* __restrict__ W2, _Float16* __restrict__ Wp2) {
    if (blockIdx.x == 1) { packW_dev(W1, Wp1, 32); return; }
    if (blockIdx.x == 2) { packW_dev(W2, Wp2, 64); return; }
    __shared__ int a[NBP];
    int t = threadIdx.x;  // 256 threads
    int cnt = 0;
    for (int b = 0; b < NHB; ++b) cnt += partial[b * NBP + t];  // coalesced across t
    a[t] = cnt;
    __syncthreads();
    for (int off = 1; off < NBP; off <<= 1) {
        int v = (t >= off) ? a[t - off] : 0;
        __syncthreads();
        a[t] += v;
        __syncthreads();
    }
    if (t < NB) {
        int incl = a[t];
        int excl = incl - cnt;
        bucketBase[t] = excl;
        bucketCur[t] = excl;
        if (t == NB - 1) bucketBase[NB] = incl;
    }
}

// tile-local counting sort by bucket, then coalesced append into global packed[]
__global__ __launch_bounds__(256) void k_redistribute(
        const int* __restrict__ src, const int* __restrict__ dst,
        int* __restrict__ bucketCur, int* __restrict__ packed, int e) {
    __shared__ int cnt[NBP], base[NBP], gdelta[NBP], lcur[NBP], a[NBP];
    __shared__ int sorted[TILE];
    __shared__ int sdelta[TILE];
    int tileBase = blockIdx.x * TILE;
    int tileCnt = min(TILE, e - tileBase);
    int t = threadIdx.x;
    for (int i = t; i < NBP; i += 256) cnt[i] = 0;
    __syncthreads();
    int pk[EPT], bk[EPT];
#pragma unroll
    for (int k = 0; k < EPT; ++k) {
        int i = k * 256 + t;
        if (i < tileCnt) {
            int d = dst[tileBase + i];
            int s = src[tileBase + i];
            bk[k] = d >> BSHIFT;
            pk[k] = (s << BSHIFT) | (d & (BNODES - 1));
            atomicAdd(&cnt[bk[k]], 1);
        } else bk[k] = -1;
    }
    __syncthreads();
    a[t] = cnt[t];
    __syncthreads();
    for (int off = 1; off < NBP; off <<= 1) {
        int v = (t >= off) ? a[t - off] : 0;
        __syncthreads();
        a[t] += v;
        __syncthreads();
    }
    base[t] = a[t] - cnt[t];
    lcur[t] = base[t];
    if (t < NB && cnt[t] > 0)
        gdelta[t] = atomicAdd(&bucketCur[t], cnt[t]) - base[t];
    __syncthreads();
#pragma unroll
    for (int k = 0; k < EPT; ++k) {
        if (bk[k] >= 0) {
            int l = atomicAdd(&lcur[bk[k]], 1);
            sorted[l] = pk[k];
            sdelta[l] = gdelta[bk[k]];
        }
    }
    __syncthreads();
    for (int i = t; i < tileCnt; i += 256)
        packed[i + sdelta[i]] = sorted[i];
}

// one WG per bucket: per-node histogram -> rowptr + dinv, local col scatter,
// FUSED: fp16 prescale of this bucket's x rows (xh1 = fp16(dinv * x))
__global__ __launch_bounds__(512) void k_bucket_csr(
        const int* __restrict__ packed, const int* __restrict__ bucketBase,
        int* __restrict__ rowptr, int* __restrict__ col, float* __restrict__ dinv,
        const float* __restrict__ X, _Float16* __restrict__ xh1,
        int n, int e) {
    __shared__ int hist[BNODES], a[BNODES], cur[BNODES];
    __shared__ float dinvS[BNODES];
    int b = blockIdx.x;
    int node0 = b * BNODES;
    int nn = min(BNODES, n - node0);
    int eb = bucketBase[b], ee = bucketBase[b + 1];
    int t = threadIdx.x;  // 512 threads
    hist[t] = 0;
    __syncthreads();
    for (int i = eb + t; i < ee; i += 512)
        atomicAdd(&hist[packed[i] & (BNODES - 1)], 1);
    __syncthreads();
    a[t] = hist[t];
    __syncthreads();
    for (int off = 1; off < BNODES; off <<= 1) {
        int v = (t >= off) ? a[t - off] : 0;
        __syncthreads();
        a[t] += v;
        __syncthreads();
    }
    int excl = a[t] - hist[t];
    cur[t] = excl;
    float di = rsqrtf((float)(1 + hist[t]));
    dinvS[t] = di;
    if (t < nn) {
        rowptr[node0 + t] = eb + excl;
        dinv[node0 + t] = di;
    }
    if (b == gridDim.x - 1 && t == 0) rowptr[n] = e;
    __syncthreads();
    // col scatter (32KB L2-local region)
    for (int i = eb + t; i < ee; i += 512) {
        int p = packed[i];
        int dl = p & (BNODES - 1);
        int l = atomicAdd(&cur[dl], 1);
        col[eb + l] = p >> BSHIFT;
    }
    // fused prescale: xh1[node] = fp16(dinv[node] * x[node]), 8 float4 per row
    const float4* X4 = (const float4*)X;
    half4* U4 = (half4*)xh1;
    for (int i = t; i < nn * 8; i += 512) {
        int nl = i >> 3;
        float4 v = X4[(size_t)(node0 + nl) * 8 + (i & 7)];
        float d2 = dinvS[nl];
        half4 h;
        h[0] = (_Float16)(v.x * d2);
        h[1] = (_Float16)(v.y * d2);
        h[2] = (_Float16)(v.z * d2);
        h[3] = (_Float16)(v.w * d2);
        U4[(size_t)(node0 + nl) * 8 + (i & 7)] = h;
    }
}

// ---------------- fused gather + MFMA GEMM layers ----------------

// Layer 1: 64 nodes/block, 4 thr/node (1 half8 each), unroll-8 edge loop.
// out = fp16(dinv * relu(agg@W1 + b1))
__global__ __launch_bounds__(256) void k_fused1(
        const _Float16* __restrict__ G, const int* __restrict__ rowptr,
        const int* __restrict__ col, const float* __restrict__ dinv,
        const _Float16* __restrict__ Wp, const float* __restrict__ bias,
        _Float16* __restrict__ out, int n) {
    __shared__ _Float16 aggS[64][40];   // stride 40 fp16 = 80B -> 2-way banks
    const int t = threadIdx.x;
    const int node0 = blockIdx.x * 64;
    {   // gather: 4 threads/node, 1 half8 each
        int nl = t >> 2, l = t & 3;
        int node = node0 + nl;
        if (node < n) {
            const half8* Gr = (const half8*)G;  // 4 half8 per 32ch row
            half8 s = Gr[(size_t)node * 4 + l];
            float acc[8];
#pragma unroll
            for (int q = 0; q < 8; ++q) acc[q] = (float)s[q];
            int jb = rowptr[node], je = rowptr[node + 1];
            int j = jb;
            for (; j + 7 < je; j += 8) {  // unroll-8: 8 row loads in flight
                half8 v[8];
#pragma unroll
                for (int u = 0; u < 8; ++u) v[u] = Gr[(size_t)col[j + u] * 4 + l];
#pragma unroll
                for (int u = 0; u < 8; ++u)
#pragma unroll
                    for (int q = 0; q < 8; ++q) acc[q] += (float)v[u][q];
            }
            for (; j + 1 < je; j += 2) {
                half8 v0 = Gr[(size_t)col[j] * 4 + l];
                half8 v1 = Gr[(size_t)col[j + 1] * 4 + l];
#pragma unroll
                for (int q = 0; q < 8; ++q) acc[q] += (float)v0[q] + (float)v1[q];
            }
            if (j < je) {
                half8 v0 = Gr[(size_t)col[j] * 4 + l];
#pragma unroll
                for (int q = 0; q < 8; ++q) acc[q] += (float)v0[q];
            }
            float di = dinv[node];
            half8 r;
#pragma unroll
            for (int q = 0; q < 8; ++q) r[q] = (_Float16)(acc[q] * di);
            *(half8*)&aggS[nl][l * 8] = r;
        }
    }
    __syncthreads();
    {   // MFMA: wave w -> nodes node0 + w*16 .. +15  (n % 16 == 0)
        const int lane = t & 63;
        const int w = t >> 6;
        int base = w * 16;
        int nw0 = node0 + base;
        if (nw0 >= n) return;
        half8 af = *(const half8*)&aggS[base + (lane & 15)][(lane >> 4) * 8];
        floatx4 z = {0.f, 0.f, 0.f, 0.f};
        floatx4 acc[4] = {z, z, z, z};
#pragma unroll
        for (int cb = 0; cb < 4; ++cb) {
            half8 bf = ((const half8*)Wp)[cb * 64 + lane];
            acc[cb] = __builtin_amdgcn_mfma_f32_16x16x32_f16(af, bf, acc[cb], 0, 0, 0);
        }
        int r0 = nw0 + (lane >> 4) * 4;
        int ch0 = lane & 15;
        float di[4];
#pragma unroll
        for (int r = 0; r < 4; ++r) di[r] = dinv[r0 + r];
#pragma unroll
        for (int cb = 0; cb < 4; ++cb) {
            int ch = cb * 16 + ch0;
            float bb = bias[ch];
#pragma unroll
            for (int r = 0; r < 4; ++r) {
                float v = acc[cb][r] + bb;
                v = v > 0.f ? v : 0.f;
                out[(size_t)(r0 + r) * 64 + ch] = (_Float16)(v * di[r]);
            }
        }
    }
}

// Layer 2: 32 nodes/block, 8 thr/node (1 half8 each), unroll-4 edge loop.
// out = f32 relu(agg@W2 + b2)
__global__ __launch_bounds__(256) void k_fused2(
        const _Float16* __restrict__ G, const int* __restrict__ rowptr,
        const int* __restrict__ col, const float* __restrict__ dinv,
        const _Float16* __restrict__ Wp, const float* __restrict__ bias,
        float* __restrict__ out, int n) {
    __shared__ _Float16 aggS[32][72];   // stride 72 fp16 = 144B -> 2-way banks
    const int t = threadIdx.x;
    const int node0 = blockIdx.x * 32;  // N % 32 == 0 (100000 = 3125*32)
    {   // gather: 8 threads/node, 1 half8 each
        int nl = t >> 3, l = t & 7;
        int node = node0 + nl;
        const half8* Gr = (const half8*)G;  // 8 half8 per 64ch row
        half8 s = Gr[(size_t)node * 8 + l];
        float acc[8];
#pragma unroll
        for (int q = 0; q < 8; ++q) acc[q] = (float)s[q];
        int jb = rowptr[node], je = rowptr[node + 1];
        int j = jb;
        for (; j + 3 < je; j += 4) {  // unroll-4: 4 row loads in flight
            half8 v0 = Gr[(size_t)col[j] * 8 + l];
            half8 v1 = Gr[(size_t)col[j + 1] * 8 + l];
            half8 v2 = Gr[(size_t)col[j + 2] * 8 + l];
            half8 v3 = Gr[(size_t)col[j + 3] * 8 + l];
#pragma unroll
            for (int q = 0; q < 8; ++q)
                acc[q] += ((float)v0[q] + (float)v1[q]) + ((float)v2[q] + (float)v3[q]);
        }
        for (; j < je; ++j) {
            half8 v0 = Gr[(size_t)col[j] * 8 + l];
#pragma unroll
            for (int q = 0; q < 8; ++q) acc[q] += (float)v0[q];
        }
        float di = dinv[node];
        half8 r;
#pragma unroll
        for (int q = 0; q < 8; ++q) r[q] = (_Float16)(acc[q] * di);
        *(half8*)&aggS[nl][l * 8] = r;
    }
    __syncthreads();
    if (t >= 128) return;
    {   // MFMA: waves 0,1 -> 16-node tiles; KS=2
        const int lane = t & 63;
        const int w = t >> 6;
        int base = w * 16;
        int nw0 = node0 + base;
        half8 af0 = *(const half8*)&aggS[base + (lane & 15)][(lane >> 4) * 8];
        half8 af1 = *(const half8*)&aggS[base + (lane & 15)][(lane >> 4) * 8 + 32];
        floatx4 z = {0.f, 0.f, 0.f, 0.f};
        floatx4 acc[4] = {z, z, z, z};
#pragma unroll
        for (int cb = 0; cb < 4; ++cb) {
            half8 bf0 = ((const half8*)Wp)[(0 * 4 + cb) * 64 + lane];
            half8 bf1 = ((const half8*)Wp)[(1 * 4 + cb) * 64 + lane];
            acc[cb] = __builtin_amdgcn_mfma_f32_16x16x32_f16(af0, bf0, acc[cb], 0, 0, 0);
            acc[cb] = __builtin_amdgcn_mfma_f32_16x16x32_f16(af1, bf1, acc[cb], 0, 0, 0);
        }
        int r0 = nw0 + (lane >> 4) * 4;
        int ch0 = lane & 15;
#pragma unroll
        for (int cb = 0; cb < 4; ++cb) {
            int ch = cb * 16 + ch0;
            float bb = bias[ch];
#pragma unroll
            for (int r = 0; r < 4; ++r) {
                float v = acc[cb][r] + bb;
                out[(size_t)(r0 + r) * 64 + ch] = v > 0.f ? v : 0.f;
            }
        }
    }
}

// ---------------- launch ----------------

extern "C" void kernel_launch(void* const* d_in, const int* in_sizes, int n_in,
                              void* d_out, int out_size, void* d_ws, size_t ws_size,
                              hipStream_t stream) {
    const float* x  = (const float*)d_in[0];
    const int* ei   = (const int*)d_in[1];   // [2, E] row-major, int32
    const float* W1 = (const float*)d_in[2];
    const float* b1 = (const float*)d_in[3];
    const float* W2 = (const float*)d_in[4];
    const float* b2 = (const float*)d_in[5];

    const int N = N_NODES;
    const int E = N_EDGES;
    const int* src = ei;       // edge_index[0]
    const int* dst = ei + E;   // edge_index[1]

    // workspace layout (512B aligned blocks)
    char* ws = (char*)d_ws;
    size_t off = 0;
    auto alloc = [&](size_t bytes) { void* p = ws + off; off = (off + bytes + 511) & ~511ull; return p; };
    int*   partial    = (int*)  alloc((size_t)NHB * NBP * 4);   // 256 KB
    int*   bucketBase = (int*)  alloc((size_t)(NB + 1) * 4);
    int*   bucketCur  = (int*)  alloc((size_t)NB * 4);
    int*   packed     = (int*)  alloc((size_t)E * 4);
    int*   rowptr     = (int*)  alloc((size_t)(N + 1) * 4);
    int*   col        = (int*)  alloc((size_t)E * 4);
    float* dinv       = (float*)alloc((size_t)N * 4);
    _Float16* Wp1     = (_Float16*)alloc((size_t)32 * 64 * 2);
    _Float16* Wp2     = (_Float16*)alloc((size_t)64 * 64 * 2);
    _Float16* xh1     = (_Float16*)alloc((size_t)N * 32 * 2);   // 6.4 MB
    _Float16* xh2     = (_Float16*)alloc((size_t)N * 64 * 2);   // 12.8 MB
    float* outF       = (float*)d_out;

    const int B = 256;
    const int nTiles = (E + TILE - 1) / TILE;        // 391

    // ---- CSR build ----
    k_hist<<<NHB, B, 0, stream>>>(dst, partial, E);
    k_bscan_pack<<<3, B, 0, stream>>>(partial, bucketBase, bucketCur, W1, Wp1, W2, Wp2);
    k_redistribute<<<nTiles, B, 0, stream>>>(src, dst, bucketCur, packed, E);
    k_bucket_csr<<<NB, BNODES, 0, stream>>>(packed, bucketBase, rowptr, col, dinv, x, xh1, N, E);

    // ---- layer 1 (gather 32ch + MFMA fused): 64 nodes/block ----
    k_fused1<<<(N + 63) / 64, B, 0, stream>>>(xh1, rowptr, col, dinv, Wp1, b1, xh2, N);

    // ---- layer 2 (gather 64ch + MFMA fused): 32 nodes/block ----
    k_fused2<<<N / 32, B, 0, stream>>>(xh2, rowptr, col, dinv, Wp2, b2, outF, N);
}